// Round 5
// baseline (481.060 us; speedup 1.0000x reference)
//
#include <hip/hip_runtime.h>

#define NN   4096
#define FIN  3000
#define MAXN 128

typedef unsigned short u16;
typedef __bf16 bf16x8 __attribute__((ext_vector_type(8)));
typedef float f32x16 __attribute__((ext_vector_type(16)));

__device__ __forceinline__ float bf2f(u16 u) { union { unsigned int i; float f; } v; v.i = ((unsigned int)u) << 16; return v.f; }
__device__ __forceinline__ u16 f2bf(float f) {
    union { float f; unsigned int i; } v; v.f = f;
    return (u16)((v.i + 0x7FFFu + ((v.i >> 16) & 1u)) >> 16);
}
__device__ __forceinline__ bf16x8 bzero8() {
    union { unsigned long long q[2]; bf16x8 v; } u; u.q[0] = 0ull; u.q[1] = 0ull; return u.v;
}
__device__ __forceinline__ f32x16 fzero16() {
    f32x16 v;
    #pragma unroll
    for (int i = 0; i < 16; i++) v[i] = 0.f;
    return v;
}

// ---- dtype detector: bf16 N(0,1) u16s have exponent ~127; f32-as-u16 halves are random.
__global__ __launch_bounds__(1024) void k_detect(const u16* __restrict__ feat, int* __restrict__ flag)
{
    __shared__ int tot;
    if (threadIdx.x == 0) tot = 0;
    __syncthreads();
    int ins = 0;
    for (int i = threadIdx.x; i < 16384; i += 1024) {
        u16 u = feat[i];
        int e = (u >> 7) & 0xFF;
        if (u != 0 && (e < 90 || e > 160)) ins++;
    }
    atomicAdd(&tot, ins);
    __syncthreads();
    if (threadIdx.x == 0) *flag = (tot > 1024) ? 1 : 0;   // 1 = inputs are f32
}

// ---- convert 16 weight tensors -> f32 arena (blockIdx.y = segment) ----
__global__ __launch_bounds__(256) void k_convw(const int* __restrict__ flag,
    const void* s0, const void* s1, const void* s2, const void* s3,
    const void* s4, const void* s5, const void* s6, const void* s7,
    const void* s8, const void* s9, const void* s10, const void* s11,
    const void* s12, const void* s13, const void* s14, const void* s15,
    float* __restrict__ dst)
{
    const void* srcs[16] = {s0,s1,s2,s3,s4,s5,s6,s7,s8,s9,s10,s11,s12,s13,s14,s15};
    const int offs[16] = {0,192000,196096,196160,196224,212608,212864,245632,245760,253952,254016,262208,262336,270528,270592,274688};
    const int ns[16]   = {192000,4096,64,64,16384,256,32768,128,8192,64,8192,128,8192,64,4096,1};
    int seg = blockIdx.y;
    int i = blockIdx.x * 256 + threadIdx.x;
    if (i >= ns[seg]) return;
    float v = (*flag) ? ((const float*)srcs[seg])[i] : bf2f(((const u16*)srcs[seg])[i]);
    dst[offs[seg] + i] = v;
}

// ---- build W2tH/W2tL = split-bf16 W2^T [3008][64] (n-major), zero-padded in n ----
__global__ __launch_bounds__(256) void k_convw2t(const int* __restrict__ flag,
    const void* __restrict__ src, u16* __restrict__ WH, u16* __restrict__ WL)
{
    int i = blockIdx.x * 256 + threadIdx.x;      // over 3008*64
    if (i >= 3008 * 64) return;
    int n = i >> 6, k = i & 63;
    float v = 0.f;
    if (n < FIN)
        v = (*flag) ? ((const float*)src)[(size_t)k * FIN + n]
                    : bf2f(((const u16*)src)[(size_t)k * FIN + n]);
    u16 h = f2bf(v);
    float r = v - bf2f(h);                       // exact in f32
    WH[i] = h;
    WL[i] = f2bf(r);
}

// ---- build BtH/BtL = split-bf16 W1^T [64][3008], zero-padded in k ----
// v = hi + lo + O(2^-18 * v): hi = bf16(v), lo = bf16(v - hi) (exact residual).
__global__ __launch_bounds__(256) void k_convw1t(const int* __restrict__ flag,
    const void* __restrict__ w1src, u16* __restrict__ BtH, u16* __restrict__ BtL)
{
    int i = blockIdx.x * 256 + threadIdx.x;      // over 64*3008
    if (i >= 64 * 3008) return;
    int c = i / 3008, k = i - c * 3008;
    float v = 0.f;
    if (k < 3000)
        v = (*flag) ? ((const float*)w1src)[(size_t)k * 64 + c]
                    : bf2f(((const u16*)w1src)[(size_t)k * 64 + c]);
    u16 h = f2bf(v);
    float r = v - bf2f(h);                       // exact in f32
    BtH[(size_t)c * 3008 + k] = h;
    BtL[(size_t)c * 3008 + k] = f2bf(r);
}

// ---- ordered CSR build (prefix-scan, deterministic, sorted) for adj / graph_neigh ----
// vectorized loads: f32 path 4x float4, u16 path 2x uint4 per thread (64B / 32B).
__global__ __launch_bounds__(256) void k_build_csr(const int* __restrict__ flag,
    const void* __restrict__ Av, const void* __restrict__ Gv,
    int* __restrict__ aCnt, int* __restrict__ aIdx,
    int* __restrict__ gCnt, int* __restrict__ gIdx)
{
    bool isf = (*flag != 0);
    const void* M = blockIdx.y ? Gv : Av;
    int* cnt = blockIdx.y ? gCnt : aCnt;
    int* idx = blockIdx.y ? gIdx : aIdx;
    int row = blockIdx.x, t = threadIdx.x;
    int c0 = t * 16;
    unsigned int mask = 0; int my = 0;
    if (isf) {
        const float4* r = (const float4*)((const float*)M + (size_t)row * NN + c0);
        union { float4 q[4]; float f[16]; } u;
        u.q[0] = r[0]; u.q[1] = r[1]; u.q[2] = r[2]; u.q[3] = r[3];
        #pragma unroll
        for (int j = 0; j < 16; j++) if (u.f[j] != 0.f) { mask |= 1u << j; my++; }
    } else {
        const uint4* r = (const uint4*)((const u16*)M + (size_t)row * NN + c0);
        union { uint4 q[2]; u16 h[16]; } u;
        u.q[0] = r[0]; u.q[1] = r[1];
        #pragma unroll
        for (int j = 0; j < 16; j++) if (u.h[j] != 0) { mask |= 1u << j; my++; }
    }
    __shared__ int sc[256];
    sc[t] = my;
    __syncthreads();
    for (int d = 1; d < 256; d <<= 1) {
        int v = (t >= d) ? sc[t - d] : 0;
        __syncthreads();
        sc[t] += v;
        __syncthreads();
    }
    int pos = sc[t] - my;
    for (int j = 0; j < 16; j++) {
        if (mask & (1u << j)) {
            if (pos < MAXN) idx[(size_t)row * MAXN + pos] = c0 + j;
            pos++;
        }
    }
    if (t == 0) { int total = sc[255]; cnt[row] = (total < MAXN) ? total : MAXN; }
}

// ---- bf16-input path: X = feat @ weight1 via 1-term v_mfma_f32_32x32x16_bf16 ----
__global__ __launch_bounds__(512) void k_featgemm_mfma(const int* __restrict__ flag,
    const void* __restrict__ F0v, const void* __restrict__ F1v,
    const u16* __restrict__ BtH, float* __restrict__ X0, float* __restrict__ X1)
{
    if (*flag) return;                     // f32 mode: handled by k_featgemm_mfma_f32
    const u16* F = (const u16*)(blockIdx.y ? F1v : F0v);
    float* X = blockIdx.y ? X1 : X0;
    int r0 = blockIdx.x * 32;
    int tid = threadIdx.x;
    int w  = tid >> 6;                     // wave id = K-eighth
    int l  = tid & 63;
    int lr = l & 31;                       // A row / B col / D col
    int kg = l >> 5;                       // k-group (0..1), 8 elems each
    const u16* arow = F   + (size_t)(r0 + lr) * FIN + kg * 8;
    const u16* b0p  = BtH + (size_t)lr * 3008 + kg * 8;
    const u16* b1p  = BtH + (size_t)(lr + 32) * 3008 + kg * 8;
    f32x16 acc0 = fzero16(), acc1 = fzero16();
    #pragma unroll 4
    for (int s = w; s < 188; s += 8) {
        int kk = s * 16;
        bf16x8 a;
        if (kk + kg * 8 < FIN) a = *(const bf16x8*)(arow + kk);
        else                   a = bzero8();
        bf16x8 b0 = *(const bf16x8*)(b0p + kk);   // Bt zero-padded to 3008
        bf16x8 b1 = *(const bf16x8*)(b1p + kk);
        acc0 = __builtin_amdgcn_mfma_f32_32x32x16_bf16(a, b0, acc0, 0, 0, 0);
        acc1 = __builtin_amdgcn_mfma_f32_32x32x16_bf16(a, b1, acc1, 0, 0, 0);
    }
    __shared__ float red[8][2048];         // 64 KB: per-wave 32x64 partials
    float* rp = red[w];
    #pragma unroll
    for (int reg = 0; reg < 16; reg++) {
        int row = (reg & 3) + 8 * (reg >> 2) + 4 * kg;
        rp[row * 64 + lr] = acc0[reg];
    }
    #pragma unroll
    for (int reg = 0; reg < 16; reg++) {
        int row = (reg & 3) + 8 * (reg >> 2) + 4 * kg;
        rp[row * 64 + 32 + lr] = acc1[reg];
    }
    __syncthreads();
    for (int i = tid; i < 2048; i += 512) {
        float s0 = 0.f;
        #pragma unroll
        for (int j = 0; j < 8; j++) s0 += red[j][i];
        X[(size_t)r0 * 64 + i] = s0;
    }
}

// ---- helpers for the pipelined f32 featgemm ----
__device__ __forceinline__ void fg_loadA(const float* __restrict__ arow, int kk,
                                         float4& A0, float4& A1)
{
    A0 = *(const float4*)(arow + kk);
    A1 = *(const float4*)(arow + kk + 4);
}
__device__ __forceinline__ void fg_loadB(
    const u16* __restrict__ b0h, const u16* __restrict__ b1h,
    const u16* __restrict__ b0l, const u16* __restrict__ b1l, int kk,
    bf16x8& H0, bf16x8& H1, bf16x8& L0, bf16x8& L1)
{
    H0 = *(const bf16x8*)(b0h + kk);
    H1 = *(const bf16x8*)(b1h + kk);
    L0 = *(const bf16x8*)(b0l + kk);
    L1 = *(const bf16x8*)(b1l + kk);
}
__device__ __forceinline__ void fg_step(
    const float4& A0, const float4& A1,
    const bf16x8& H0, const bf16x8& H1, const bf16x8& L0, const bf16x8& L1,
    f32x16& acc0, f32x16& acc1)
{
    float av[8] = {A0.x, A0.y, A0.z, A0.w, A1.x, A1.y, A1.z, A1.w};
    bf16x8 ah, al;
    #pragma unroll
    for (int j = 0; j < 8; j++) {
        __bf16 hv = (__bf16)av[j];
        ah[j] = hv;
        al[j] = (__bf16)(av[j] - (float)hv);     // exact residual
    }
    acc0 = __builtin_amdgcn_mfma_f32_32x32x16_bf16(ah, H0, acc0, 0, 0, 0);
    acc0 = __builtin_amdgcn_mfma_f32_32x32x16_bf16(al, H0, acc0, 0, 0, 0);
    acc0 = __builtin_amdgcn_mfma_f32_32x32x16_bf16(ah, L0, acc0, 0, 0, 0);
    acc1 = __builtin_amdgcn_mfma_f32_32x32x16_bf16(ah, H1, acc1, 0, 0, 0);
    acc1 = __builtin_amdgcn_mfma_f32_32x32x16_bf16(al, H1, acc1, 0, 0, 0);
    acc1 = __builtin_amdgcn_mfma_f32_32x32x16_bf16(ah, L1, acc1, 0, 0, 0);
}

// ---- f32-input path: X = feat @ weight1 via split-bf16 3-term MFMA ----
// Round-5 restructure (round-4 post-mortem: loads under runtime conditionals
// never pipelined; 60/70 µs pure latency wait, all pipes <8% busy):
//  * 16 K-chunks x 12 steps; chunks 0..14 have NO bounds checks in the loop
//    (s<=179 -> kk+16<=2880<3000 always); only chunk 15 runs a guarded tail.
//  * depth-3 rotating register buffers, fully unrolled: 12 loads in flight/wave,
//    2 MFMA-steps between issue and use.
//  * no LDS, no barriers: waves own disjoint 32-row tiles; K-reduce via
//    atomicAdd (32 MB, L2-resident). 4 blocks/CU occupancy (was 2, LDS-capped).
__global__ __launch_bounds__(256) void k_featgemm_mfma_f32(const int* __restrict__ flag,
    const void* __restrict__ F0v, const void* __restrict__ F1v,
    const u16* __restrict__ BtH, const u16* __restrict__ BtL,
    float* __restrict__ X0, float* __restrict__ X1)
{
    if (!*flag) return;                    // bf16 mode: handled by k_featgemm_mfma
    const float* F = (const float*)(blockIdx.y ? F1v : F0v);
    float* X = blockIdx.y ? X1 : X0;
    int tid = threadIdx.x;
    int w  = tid >> 6;                     // wave id: owns rows r0..r0+31
    int l  = tid & 63;
    int lr = l & 31;                       // A row / B col / D col
    int kg = l >> 5;                       // k-group (0..1), 8 elems each
    int r0 = blockIdx.x * 128 + w * 32;
    int chunk = blockIdx.z;                // 0..15, chunk c covers s = c*12..c*12+11
    const float* arow = F + (size_t)(r0 + lr) * FIN + kg * 8;
    const u16* b0h = BtH + (size_t)lr * 3008 + kg * 8;
    const u16* b1h = BtH + (size_t)(lr + 32) * 3008 + kg * 8;
    const u16* b0l = BtL + (size_t)lr * 3008 + kg * 8;
    const u16* b1l = BtL + (size_t)(lr + 32) * 3008 + kg * 8;
    f32x16 acc0 = fzero16(), acc1 = fzero16();

    if (chunk < 15) {
        // clean path: no conditionals anywhere in the loop body
        int sbase = chunk * 12;
        float4 A0[3], A1[3];
        bf16x8 H0[3], H1[3], L0[3], L1[3];
        fg_loadA(arow, (sbase + 0) * 16, A0[0], A1[0]);
        fg_loadB(b0h, b1h, b0l, b1l, (sbase + 0) * 16, H0[0], H1[0], L0[0], L1[0]);
        fg_loadA(arow, (sbase + 1) * 16, A0[1], A1[1]);
        fg_loadB(b0h, b1h, b0l, b1l, (sbase + 1) * 16, H0[1], H1[1], L0[1], L1[1]);
        #pragma unroll
        for (int j = 0; j < 12; j++) {     // full unroll: all buffer idx compile-time
            int cur = j % 3, nxt = (j + 2) % 3;
            if (j < 10) {
                int kk = (sbase + j + 2) * 16;
                fg_loadA(arow, kk, A0[nxt], A1[nxt]);
                fg_loadB(b0h, b1h, b0l, b1l, kk, H0[nxt], H1[nxt], L0[nxt], L1[nxt]);
            }
            fg_step(A0[cur], A1[cur], H0[cur], H1[cur], L0[cur], L1[cur], acc0, acc1);
        }
    } else {
        // tail: s = 180..187; only s=187,kg=1 needs masking (A-load would cross
        // the tensor end on the last row), B is zero-padded to 3008.
        for (int s = 180; s < 188; s++) {
            int kk = s * 16;
            float4 A0v, A1v;
            if (kk + kg * 8 < FIN) {
                A0v = *(const float4*)(arow + kk);
                A1v = *(const float4*)(arow + kk + 4);
            } else {
                A0v = make_float4(0.f, 0.f, 0.f, 0.f);
                A1v = make_float4(0.f, 0.f, 0.f, 0.f);
            }
            bf16x8 H0v, H1v, L0v, L1v;
            fg_loadB(b0h, b1h, b0l, b1l, kk, H0v, H1v, L0v, L1v);
            fg_step(A0v, A1v, H0v, H1v, L0v, L1v, acc0, acc1);
        }
    }

    // K-reduce across the 16 chunks via atomics (X pre-zeroed; L2-resident).
    #pragma unroll
    for (int reg = 0; reg < 16; reg++) {
        int row = (reg & 3) + 8 * (reg >> 2) + 4 * kg;
        float* xp = X + (size_t)(r0 + row) * 64;
        atomicAdd(xp + lr, acc0[reg]);
        atomicAdd(xp + 32 + lr, acc1[reg]);
    }
}

// ---- Wh = X @ att_W; s = Wh@a_src; d = Wh@a_dst (all-f32) ----
__global__ __launch_bounds__(64) void k_whsd(
    const float* __restrict__ X1, const float* __restrict__ X2,
    const float* __restrict__ AW, const float* __restrict__ asrc, const float* __restrict__ adst,
    float* __restrict__ Wh1, float* __restrict__ Wh2,
    float* __restrict__ s1, float* __restrict__ s2,
    float* __restrict__ d1, float* __restrict__ d2)
{
    const float* X = blockIdx.y ? X2 : X1;
    float* Wh = blockIdx.y ? Wh2 : Wh1;
    float* sv = blockIdx.y ? s2 : s1;
    float* dv = blockIdx.y ? d2 : d1;
    int row = blockIdx.x, c = threadIdx.x;
    __shared__ float x[64];
    x[c] = X[(size_t)row * 64 + c];
    __syncthreads();
    float acc = 0.f;
    #pragma unroll 16
    for (int k = 0; k < 64; k++) acc += x[k] * AW[k * 64 + c];
    Wh[(size_t)row * 64 + c] = acc;
    float vs = acc * asrc[c];
    float vd = acc * adst[c];
    #pragma unroll
    for (int off = 32; off > 0; off >>= 1) { vs += __shfl_down(vs, off); vd += __shfl_down(vd, off); }
    if (c == 0) { sv[row] = vs; dv[row] = vd; }
}

// ---- masked softmax (rank-1 scores) + P @ Wh over CSR neighbors ----
__global__ __launch_bounds__(128) void k_attn(
    const int* __restrict__ cnt, const int* __restrict__ idx,
    const float* __restrict__ s1, const float* __restrict__ s2,
    const float* __restrict__ d1, const float* __restrict__ d2,
    const float* __restrict__ Wh1, const float* __restrict__ Wh2,
    float* __restrict__ A1, float* __restrict__ A2)
{
    const float* sp = blockIdx.y ? s2 : s1;
    const float* dp = blockIdx.y ? d2 : d1;
    const float* Wh = blockIdx.y ? Wh2 : Wh1;
    float* A = blockIdx.y ? A2 : A1;
    int row = blockIdx.x, tid = threadIdx.x;
    int n = cnt[row];
    __shared__ int js[MAXN];
    __shared__ float ps[MAXN];
    __shared__ float red2[2];
    __shared__ float ared[2][64];
    for (int k = tid; k < n; k += 128) js[k] = idx[(size_t)row * MAXN + k];
    __syncthreads();
    float si = sp[row];
    float m = -3.0e38f;
    for (int k = tid; k < n; k += 128) {
        float e = si + dp[js[k]];
        e = e > 0.f ? e : 0.2f * e;   // LeakyReLU(0.2)
        ps[k] = e;
        m = fmaxf(m, e);
    }
    #pragma unroll
    for (int off = 32; off > 0; off >>= 1) m = fmaxf(m, __shfl_down(m, off));
    if ((tid & 63) == 0) red2[tid >> 6] = m;
    __syncthreads();
    m = fmaxf(red2[0], red2[1]);
    __syncthreads();
    float zz = 0.f;
    for (int k = tid; k < n; k += 128) {
        float p = __expf(ps[k] - m);
        ps[k] = p;
        zz += p;
    }
    #pragma unroll
    for (int off = 32; off > 0; off >>= 1) zz += __shfl_down(zz, off);
    if ((tid & 63) == 0) red2[tid >> 6] = zz;
    __syncthreads();
    float Z = red2[0] + red2[1];
    Z = fmaxf(Z, 1e-20f);           // guard 0/0
    int f = tid & 63, half = tid >> 6;
    float acc = 0.f;
    for (int k = half; k < n; k += 2) acc += ps[k] * Wh[(size_t)js[k] * 64 + f];
    ared[half][f] = acc;
    __syncthreads();
    if (tid < 64) A[(size_t)row * 64 + f] = (ared[0][f] + ared[1][f]) / Z;
}

// ---- 3-layer MLP 64->256->128->64; 4 rows/block; writes z (f32) and hiden_emb (dual-dtype, y==0) ----
__global__ __launch_bounds__(256) void k_mlp(const int* __restrict__ flag,
    const float* __restrict__ A1, const float* __restrict__ A2,
    const float* __restrict__ W1, const float* __restrict__ b1,
    const float* __restrict__ W2, const float* __restrict__ b2,
    const float* __restrict__ W3, const float* __restrict__ b3,
    float* __restrict__ Z1, float* __restrict__ Z2, void* __restrict__ hidenv)
{
    const float* A = blockIdx.y ? A2 : A1;
    float* Z = blockIdx.y ? Z2 : Z1;
    int row0 = blockIdx.x * 4, tid = threadIdx.x;
    __shared__ float x[4][64], h1[4][256], h2[4][128];
    {
        int r = tid >> 6, c = tid & 63;
        x[r][c] = A[(size_t)(row0 + r) * 64 + c];
    }
    __syncthreads();
    {
        float a0 = b1[tid], a1v = a0, a2v = a0, a3v = a0;
        #pragma unroll 8
        for (int k = 0; k < 64; k++) {
            float w = W1[k * 256 + tid];
            a0 += x[0][k] * w; a1v += x[1][k] * w; a2v += x[2][k] * w; a3v += x[3][k] * w;
        }
        h1[0][tid] = fmaxf(a0, 0.f);  h1[1][tid] = fmaxf(a1v, 0.f);
        h1[2][tid] = fmaxf(a2v, 0.f); h1[3][tid] = fmaxf(a3v, 0.f);
    }
    __syncthreads();
    if (tid < 128) {
        float a0 = b2[tid], a1v = a0, a2v = a0, a3v = a0;
        #pragma unroll 8
        for (int k = 0; k < 256; k++) {
            float w = W2[k * 128 + tid];
            a0 += h1[0][k] * w; a1v += h1[1][k] * w; a2v += h1[2][k] * w; a3v += h1[3][k] * w;
        }
        h2[0][tid] = fmaxf(a0, 0.f);  h2[1][tid] = fmaxf(a1v, 0.f);
        h2[2][tid] = fmaxf(a2v, 0.f); h2[3][tid] = fmaxf(a3v, 0.f);
    }
    __syncthreads();
    if (tid < 64) {
        float a[4];
        a[0] = a[1] = a[2] = a[3] = b3[tid];
        #pragma unroll 8
        for (int k = 0; k < 128; k++) {
            float w = W3[k * 64 + tid];
            a[0] += h2[0][k] * w; a[1] += h2[1][k] * w; a[2] += h2[2][k] * w; a[3] += h2[3][k] * w;
        }
        bool isf = (*flag != 0);
        #pragma unroll
        for (int r = 0; r < 4; r++) {
            size_t ei = (size_t)(row0 + r) * 64 + tid;
            Z[ei] = a[r];
            if (blockIdx.y == 0) {
                if (isf) ((float*)hidenv)[ei] = a[r];
                else     ((u16*)hidenv)[ei] = f2bf(a[r]);
            }
        }
    }
}

// ---- T = adj @ z over CSR ----
__global__ __launch_bounds__(64) void k_spmm(
    const int* __restrict__ cnt, const int* __restrict__ idx,
    const float* __restrict__ Z, float* __restrict__ T)
{
    int row = blockIdx.x, f = threadIdx.x;
    int n = cnt[row];
    const int* ir = idx + (size_t)row * MAXN;
    float acc = 0.f;
    for (int k = 0; k < n; k++) acc += Z[(size_t)ir[k] * 64 + f];
    T[(size_t)row * 64 + f] = acc;
}

// ---- H = T @ weight2 via split-bf16 3-term MFMA -> out (dual-dtype store) ----
__global__ __launch_bounds__(256) void k_hgemm_mfma(const int* __restrict__ flag,
    const float* __restrict__ T, const u16* __restrict__ WH, const u16* __restrict__ WL,
    void* __restrict__ outv)
{
    bool isf = (*flag != 0);
    int tid = threadIdx.x;
    int w = tid >> 6, l = tid & 63, lr = l & 31, kg = l >> 5;
    int ct = blockIdx.y * 4 + w;
    if (ct >= 94) return;                  // wave-uniform; no barriers in kernel
    int r0 = blockIdx.x * 32, c0 = ct * 32;
    const float* tp = T + (size_t)(r0 + lr) * 64 + kg * 8;
    bf16x8 ah[4], al[4];
    #pragma unroll
    for (int s = 0; s < 4; s++) {
        float4 p0 = *(const float4*)(tp + s * 16);
        float4 p1 = *(const float4*)(tp + s * 16 + 4);
        float av[8] = {p0.x, p0.y, p0.z, p0.w, p1.x, p1.y, p1.z, p1.w};
        #pragma unroll
        for (int j = 0; j < 8; j++) {
            __bf16 hv = (__bf16)av[j];
            ah[s][j] = hv;
            al[s][j] = (__bf16)(av[j] - (float)hv);   // exact residual
        }
    }
    const u16* bh = WH + (size_t)(c0 + lr) * 64 + kg * 8;
    const u16* bl = WL + (size_t)(c0 + lr) * 64 + kg * 8;
    f32x16 acc = fzero16();
    #pragma unroll
    for (int s = 0; s < 4; s++) {
        bf16x8 vh = *(const bf16x8*)(bh + s * 16);
        bf16x8 vl = *(const bf16x8*)(bl + s * 16);
        acc = __builtin_amdgcn_mfma_f32_32x32x16_bf16(ah[s], vh, acc, 0, 0, 0);
        acc = __builtin_amdgcn_mfma_f32_32x32x16_bf16(al[s], vh, acc, 0, 0, 0);
        acc = __builtin_amdgcn_mfma_f32_32x32x16_bf16(ah[s], vl, acc, 0, 0, 0);
    }
    int col = c0 + lr;
    bool cok = col < FIN;
    #pragma unroll
    for (int reg = 0; reg < 16; reg++) {
        int row = (reg & 3) + 8 * (reg >> 2) + 4 * kg;
        size_t ei = 262144 + (size_t)(r0 + row) * FIN + col;
        if (cok) {
            if (isf) ((float*)outv)[ei] = acc[reg];
            else     ((u16*)outv)[ei] = f2bf(acc[reg]);
        }
    }
}

// ---- readout: mean over graph_neigh nbrs of relu(z), L2 normalize, sigmoid ----
__global__ __launch_bounds__(64) void k_readout(
    const int* __restrict__ cnt, const int* __restrict__ idx,
    const float* __restrict__ Z1, const float* __restrict__ Z2,
    float* __restrict__ G1, float* __restrict__ G2)
{
    const float* Z = blockIdx.y ? Z2 : Z1;
    float* G = blockIdx.y ? G2 : G1;
    int row = blockIdx.x, f = threadIdx.x;
    int n = cnt[row];
    const int* ir = idx + (size_t)row * MAXN;
    float acc = 0.f;
    for (int k = 0; k < n; k++) acc += fmaxf(Z[(size_t)ir[k] * 64 + f], 0.f);
    acc /= (float)(n > 0 ? n : 1);
    float sq = acc * acc;
    #pragma unroll
    for (int off = 32; off > 0; off >>= 1) sq += __shfl_down(sq, off);
    sq = __shfl(sq, 0);
    float nrm = fmaxf(sqrtf(sq), 1e-12f);
    float v = acc / nrm;
    G[(size_t)row * 64 + f] = 1.f / (1.f + __expf(-v));
}

// ---- discriminator MLP 64->128->64; 4 rows/block; on {relu(z), relu(z_a), g, g_a} ----
__global__ __launch_bounds__(128) void k_dmlp(
    const float* __restrict__ z, const float* __restrict__ za,
    const float* __restrict__ g, const float* __restrict__ ga,
    const float* __restrict__ W1, const float* __restrict__ b1,
    const float* __restrict__ W2, const float* __restrict__ b2,
    float* __restrict__ De, float* __restrict__ Dea,
    float* __restrict__ Dg, float* __restrict__ Dga)
{
    int w = blockIdx.y;
    const float* X = (w == 0) ? z : (w == 1) ? za : (w == 2) ? g : ga;
    float* O = (w == 0) ? De : (w == 1) ? Dea : (w == 2) ? Dg : Dga;
    int doRelu = (w < 2);
    int row0 = blockIdx.x * 4, tid = threadIdx.x;
    __shared__ float x[4][64], h1[4][128];
    for (int i = tid; i < 256; i += 128) {
        int r = i >> 6, c = i & 63;
        float v = X[(size_t)(row0 + r) * 64 + c];
        x[r][c] = doRelu ? fmaxf(v, 0.f) : v;
    }
    __syncthreads();
    {
        float a0 = b1[tid], a1v = a0, a2v = a0, a3v = a0;
        #pragma unroll 8
        for (int k = 0; k < 64; k++) {
            float w_ = W1[k * 128 + tid];
            a0 += x[0][k] * w_; a1v += x[1][k] * w_; a2v += x[2][k] * w_; a3v += x[3][k] * w_;
        }
        h1[0][tid] = fmaxf(a0, 0.f);  h1[1][tid] = fmaxf(a1v, 0.f);
        h1[2][tid] = fmaxf(a2v, 0.f); h1[3][tid] = fmaxf(a3v, 0.f);
    }
    __syncthreads();
    if (tid < 64) {
        float a[4];
        a[0] = a[1] = a[2] = a[3] = b2[tid];
        #pragma unroll 8
        for (int k = 0; k < 128; k++) {
            float w_ = W2[k * 64 + tid];
            a[0] += h1[0][k] * w_; a[1] += h1[1][k] * w_; a[2] += h1[2][k] * w_; a[3] += h1[3][k] * w_;
        }
        #pragma unroll
        for (int r = 0; r < 4; r++) O[(size_t)(row0 + r) * 64 + tid] = a[r];
    }
}

// ---- bilinear: out = x . (bil_W @ y) + b ; dual-dtype store ----
__global__ __launch_bounds__(64) void k_bilin(const int* __restrict__ flag,
    const float* __restrict__ De, const float* __restrict__ Dea,
    const float* __restrict__ Dg, const float* __restrict__ Dga,
    const float* __restrict__ BW, const float* __restrict__ bb, void* __restrict__ outv)
{
    int w = blockIdx.y;
    const float* X = (w == 0 || w == 3) ? De : Dea;
    const float* Y = (w <= 1) ? Dg : Dga;
    size_t bse = (w <= 1) ? (size_t)12550144 : (size_t)12558336;
    int col = (w == 0 || w == 2) ? 0 : 1;
    int row = blockIdx.x, k = threadIdx.x;
    __shared__ float x[64], y[64];
    x[k] = X[(size_t)row * 64 + k];
    y[k] = Y[(size_t)row * 64 + k];
    __syncthreads();
    float wv = 0.f;
    #pragma unroll 8
    for (int j = 0; j < 64; j++) wv += BW[k * 64 + j] * y[j];
    float v = x[k] * wv;
    #pragma unroll
    for (int off = 32; off > 0; off >>= 1) v += __shfl_down(v, off);
    if (k == 0) {
        float r = v + bb[0];
        size_t ei = bse + (size_t)row * 2 + col;
        if (*flag) ((float*)outv)[ei] = r;
        else       ((u16*)outv)[ei] = f2bf(r);
    }
}

extern "C" void kernel_launch(void* const* d_in, const int* in_sizes, int n_in,
                              void* d_out, int out_size, void* d_ws, size_t ws_size,
                              hipStream_t stream) {
    const void* feat   = d_in[0];
    const void* feat_a = d_in[1];
    const void* adj    = d_in[2];
    const void* gn     = d_in[3];
    const void* w1     = d_in[4];
    const void* w2     = d_in[5];
    const void* attW   = d_in[6];
    const void* a_src  = d_in[7];
    const void* a_dst  = d_in[8];
    const void* mW1    = d_in[9];
    const void* mb1    = d_in[10];
    const void* mW2    = d_in[11];
    const void* mb2    = d_in[12];
    const void* mW3    = d_in[13];
    const void* mb3    = d_in[14];
    const void* dW1    = d_in[15];
    const void* db1    = d_in[16];
    const void* dW2    = d_in[17];
    const void* db2    = d_in[18];
    const void* bW     = d_in[19];
    const void* bb     = d_in[20];
    (void)in_sizes; (void)n_in; (void)out_size;

    // ---- d_ws: flag + T + W2tH/W2tL (~1.82 MB total) ----
    char* wsb = (char*)d_ws;
    int*   flag = (int*)wsb;                        // 4 B (pad 256)
    float* T    = (float*)(wsb + 256);              // 1,048,576 B
    u16*   W2tH = (u16*)(wsb + 256 + 1048576);      // 385,024 B
    u16*   W2tL = W2tH + 3008 * 64;                 // 385,024 B
    (void)ws_size;

    // ---- scratch arena at dtype-independent byte window of d_out:
    // bytes [1,048,576 , 21,200,000) lie inside the h output region for BOTH
    // bf16 (h bytes [524288,25100288)) and f32 (h bytes [1048576,50200576)),
    // and are fully overwritten by k_hgemm_mfma at the end.
    char* sc = (char*)d_out + 1048576;
    size_t soff = 0;
    auto salloc = [&](size_t nbytes) -> void* {
        void* p = (void*)(sc + soff);
        soff += (nbytes + 255) & ~(size_t)255;
        return p;
    };
    const size_t NV = (size_t)NN * 64;
    float* wA   = (float*)salloc((size_t)274689 * 4);  // 16-segment f32 weight arena
    int*   aCnt = (int*)salloc(NN * 4);
    int*   gCnt = (int*)salloc(NN * 4);
    int*   aIdx = (int*)salloc((size_t)NN * MAXN * 4);
    int*   gIdx = (int*)salloc((size_t)NN * MAXN * 4);
    float* X1  = (float*)salloc(NV * 4);
    float* X2  = (float*)salloc(NV * 4);   // contiguous with X1 (NV*4 is 256-mult)
    float* Wh1 = (float*)salloc(NV * 4);
    float* Wh2 = (float*)salloc(NV * 4);
    float* A1  = (float*)salloc(NV * 4);
    float* A2  = (float*)salloc(NV * 4);
    float* z   = (float*)salloc(NV * 4);
    float* za  = (float*)salloc(NV * 4);
    float* g   = (float*)salloc(NV * 4);
    float* ga  = (float*)salloc(NV * 4);
    float* De  = (float*)salloc(NV * 4);
    float* Dea = (float*)salloc(NV * 4);
    float* Dg  = (float*)salloc(NV * 4);
    float* Dga = (float*)salloc(NV * 4);
    float* s1  = (float*)salloc(NN * 4);
    float* s2  = (float*)salloc(NN * 4);
    float* d1  = (float*)salloc(NN * 4);
    float* d2  = (float*)salloc(NN * 4);
    // soff ~= 20.1 MB < 20.15 MB window: fits.

    float* w1f   = wA + 0;
    float* attWf = wA + 192000;
    float* asrcf = wA + 196096;
    float* adstf = wA + 196160;
    float* mW1f  = wA + 196224;
    float* mb1f  = wA + 212608;
    float* mW2f  = wA + 212864;
    float* mb2f  = wA + 245632;
    float* mW3f  = wA + 245760;
    float* mb3f  = wA + 253952;
    float* dW1f  = wA + 254016;
    float* db1f  = wA + 262208;
    float* dW2f  = wA + 262336;
    float* db2f  = wA + 270528;
    float* bWf   = wA + 270592;
    float* bbf   = wA + 274688;

    // BtH/BtL (split-bf16 W1^T [64][3008], 385 KB each) park in the De/Dea
    // slots: those are not written until k_dmlp, long after the feat GEMM.
    u16* BtH = (u16*)De;
    u16* BtL = (u16*)Dea;

    k_detect<<<1, 1024, 0, stream>>>((const u16*)feat, flag);
    k_convw<<<dim3(750, 16), 256, 0, stream>>>(flag,
        w1, attW, a_src, a_dst, mW1, mb1, mW2, mb2, mW3, mb3,
        dW1, db1, dW2, db2, bW, bb, wA);
    k_convw2t<<<752, 256, 0, stream>>>(flag, w2, W2tH, W2tL);
    k_convw1t<<<752, 256, 0, stream>>>(flag, w1, BtH, BtL);
    k_build_csr<<<dim3(NN, 2), 256, 0, stream>>>(flag, adj, gn, aCnt, aIdx, gCnt, gIdx);
    hipMemsetAsync(X1, 0, 2 * NV * 4, stream);   // zero X1+X2 for f32 K-split atomics
    k_featgemm_mfma<<<dim3(NN / 32, 2), 512, 0, stream>>>(flag, feat, feat_a, BtH, X1, X2);
    k_featgemm_mfma_f32<<<dim3(NN / 128, 2, 16), 256, 0, stream>>>(flag, feat, feat_a, BtH, BtL, X1, X2);
    k_whsd<<<dim3(NN, 2), 64, 0, stream>>>(X1, X2, attWf, asrcf, adstf, Wh1, Wh2, s1, s2, d1, d2);
    k_attn<<<dim3(NN, 2), 128, 0, stream>>>(aCnt, aIdx, s1, s2, d1, d2, Wh1, Wh2, A1, A2);
    k_mlp<<<dim3(NN / 4, 2), 256, 0, stream>>>(flag, A1, A2, mW1f, mb1f, mW2f, mb2f, mW3f, mb3f, z, za, d_out);
    k_readout<<<dim3(NN, 2), 64, 0, stream>>>(gCnt, gIdx, z, za, g, ga);
    k_dmlp<<<dim3(NN / 4, 4), 128, 0, stream>>>(z, za, g, ga, dW1f, db1f, dW2f, db2f, De, Dea, Dg, Dga);
    k_bilin<<<dim3(NN, 4), 64, 0, stream>>>(flag, De, Dea, Dg, Dga, bWf, bbf, d_out);
    k_spmm<<<NN, 64, 0, stream>>>(aCnt, aIdx, z, T);
    k_hgemm_mfma<<<dim3(NN / 32, 24), 256, 0, stream>>>(flag, T, W2tH, W2tL, d_out);
}

// Round 6
// 461.601 us; speedup vs baseline: 1.0422x; 1.0422x over previous
//
#include <hip/hip_runtime.h>

#define NN   4096
#define FIN  3000
#define MAXN 128

typedef unsigned short u16;
typedef __bf16 bf16x8 __attribute__((ext_vector_type(8)));
typedef float f32x16 __attribute__((ext_vector_type(16)));

__device__ __forceinline__ float bf2f(u16 u) { union { unsigned int i; float f; } v; v.i = ((unsigned int)u) << 16; return v.f; }
__device__ __forceinline__ u16 f2bf(float f) {
    union { float f; unsigned int i; } v; v.f = f;
    return (u16)((v.i + 0x7FFFu + ((v.i >> 16) & 1u)) >> 16);
}
__device__ __forceinline__ bf16x8 bzero8() {
    union { unsigned long long q[2]; bf16x8 v; } u; u.q[0] = 0ull; u.q[1] = 0ull; return u.v;
}
__device__ __forceinline__ f32x16 fzero16() {
    f32x16 v;
    #pragma unroll
    for (int i = 0; i < 16; i++) v[i] = 0.f;
    return v;
}
// async global->LDS, 16B per lane; dest = ldsbase + lane*16 (HW-fixed layout)
__device__ __forceinline__ void gload_lds16(const float* src, void* ldsbase) {
    __builtin_amdgcn_global_load_lds(
        (const __attribute__((address_space(1))) void*)src,
        (__attribute__((address_space(3))) void*)ldsbase, 16, 0, 0);
}

// ---- dtype detector: bf16 N(0,1) u16s have exponent ~127; f32-as-u16 halves are random.
__global__ __launch_bounds__(1024) void k_detect(const u16* __restrict__ feat, int* __restrict__ flag)
{
    __shared__ int tot;
    if (threadIdx.x == 0) tot = 0;
    __syncthreads();
    int ins = 0;
    for (int i = threadIdx.x; i < 16384; i += 1024) {
        u16 u = feat[i];
        int e = (u >> 7) & 0xFF;
        if (u != 0 && (e < 90 || e > 160)) ins++;
    }
    atomicAdd(&tot, ins);
    __syncthreads();
    if (threadIdx.x == 0) *flag = (tot > 1024) ? 1 : 0;   // 1 = inputs are f32
}

// ---- convert 16 weight tensors -> f32 arena (blockIdx.y = segment) ----
__global__ __launch_bounds__(256) void k_convw(const int* __restrict__ flag,
    const void* s0, const void* s1, const void* s2, const void* s3,
    const void* s4, const void* s5, const void* s6, const void* s7,
    const void* s8, const void* s9, const void* s10, const void* s11,
    const void* s12, const void* s13, const void* s14, const void* s15,
    float* __restrict__ dst)
{
    const void* srcs[16] = {s0,s1,s2,s3,s4,s5,s6,s7,s8,s9,s10,s11,s12,s13,s14,s15};
    const int offs[16] = {0,192000,196096,196160,196224,212608,212864,245632,245760,253952,254016,262208,262336,270528,270592,274688};
    const int ns[16]   = {192000,4096,64,64,16384,256,32768,128,8192,64,8192,128,8192,64,4096,1};
    int seg = blockIdx.y;
    int i = blockIdx.x * 256 + threadIdx.x;
    if (i >= ns[seg]) return;
    float v = (*flag) ? ((const float*)srcs[seg])[i] : bf2f(((const u16*)srcs[seg])[i]);
    dst[offs[seg] + i] = v;
}

// ---- build W2tH/W2tL = split-bf16 W2^T [3008][64] (n-major), zero-padded in n ----
__global__ __launch_bounds__(256) void k_convw2t(const int* __restrict__ flag,
    const void* __restrict__ src, u16* __restrict__ WH, u16* __restrict__ WL)
{
    int i = blockIdx.x * 256 + threadIdx.x;      // over 3008*64
    if (i >= 3008 * 64) return;
    int n = i >> 6, k = i & 63;
    float v = 0.f;
    if (n < FIN)
        v = (*flag) ? ((const float*)src)[(size_t)k * FIN + n]
                    : bf2f(((const u16*)src)[(size_t)k * FIN + n]);
    u16 h = f2bf(v);
    float r = v - bf2f(h);                       // exact in f32
    WH[i] = h;
    WL[i] = f2bf(r);
}

// ---- build BtH/BtL = split-bf16 W1^T [64][3008], zero-padded in k ----
// v = hi + lo + O(2^-18 * v): hi = bf16(v), lo = bf16(v - hi) (exact residual).
__global__ __launch_bounds__(256) void k_convw1t(const int* __restrict__ flag,
    const void* __restrict__ w1src, u16* __restrict__ BtH, u16* __restrict__ BtL)
{
    int i = blockIdx.x * 256 + threadIdx.x;      // over 64*3008
    if (i >= 64 * 3008) return;
    int c = i / 3008, k = i - c * 3008;
    float v = 0.f;
    if (k < 3000)
        v = (*flag) ? ((const float*)w1src)[(size_t)k * 64 + c]
                    : bf2f(((const u16*)w1src)[(size_t)k * 64 + c]);
    u16 h = f2bf(v);
    float r = v - bf2f(h);                       // exact in f32
    BtH[(size_t)c * 3008 + k] = h;
    BtL[(size_t)c * 3008 + k] = f2bf(r);
}

// ---- ordered CSR build (prefix-scan, deterministic, sorted) for adj / graph_neigh ----
__global__ __launch_bounds__(256) void k_build_csr(const int* __restrict__ flag,
    const void* __restrict__ Av, const void* __restrict__ Gv,
    int* __restrict__ aCnt, int* __restrict__ aIdx,
    int* __restrict__ gCnt, int* __restrict__ gIdx)
{
    bool isf = (*flag != 0);
    const void* M = blockIdx.y ? Gv : Av;
    int* cnt = blockIdx.y ? gCnt : aCnt;
    int* idx = blockIdx.y ? gIdx : aIdx;
    int row = blockIdx.x, t = threadIdx.x;
    int c0 = t * 16;
    unsigned int mask = 0; int my = 0;
    if (isf) {
        const float4* r = (const float4*)((const float*)M + (size_t)row * NN + c0);
        union { float4 q[4]; float f[16]; } u;
        u.q[0] = r[0]; u.q[1] = r[1]; u.q[2] = r[2]; u.q[3] = r[3];
        #pragma unroll
        for (int j = 0; j < 16; j++) if (u.f[j] != 0.f) { mask |= 1u << j; my++; }
    } else {
        const uint4* r = (const uint4*)((const u16*)M + (size_t)row * NN + c0);
        union { uint4 q[2]; u16 h[16]; } u;
        u.q[0] = r[0]; u.q[1] = r[1];
        #pragma unroll
        for (int j = 0; j < 16; j++) if (u.h[j] != 0) { mask |= 1u << j; my++; }
    }
    __shared__ int sc[256];
    sc[t] = my;
    __syncthreads();
    for (int d = 1; d < 256; d <<= 1) {
        int v = (t >= d) ? sc[t - d] : 0;
        __syncthreads();
        sc[t] += v;
        __syncthreads();
    }
    int pos = sc[t] - my;
    for (int j = 0; j < 16; j++) {
        if (mask & (1u << j)) {
            if (pos < MAXN) idx[(size_t)row * MAXN + pos] = c0 + j;
            pos++;
        }
    }
    if (t == 0) { int total = sc[255]; cnt[row] = (total < MAXN) ? total : MAXN; }
}

// ---- bf16-input path: X = feat @ weight1 via 1-term v_mfma_f32_32x32x16_bf16 ----
__global__ __launch_bounds__(512) void k_featgemm_mfma(const int* __restrict__ flag,
    const void* __restrict__ F0v, const void* __restrict__ F1v,
    const u16* __restrict__ BtH, float* __restrict__ X0, float* __restrict__ X1)
{
    if (*flag) return;                     // f32 mode: handled by k_featgemm_mfma_f32
    const u16* F = (const u16*)(blockIdx.y ? F1v : F0v);
    float* X = blockIdx.y ? X1 : X0;
    int r0 = blockIdx.x * 32;
    int tid = threadIdx.x;
    int w  = tid >> 6;                     // wave id = K-eighth
    int l  = tid & 63;
    int lr = l & 31;                       // A row / B col / D col
    int kg = l >> 5;                       // k-group (0..1), 8 elems each
    const u16* arow = F   + (size_t)(r0 + lr) * FIN + kg * 8;
    const u16* b0p  = BtH + (size_t)lr * 3008 + kg * 8;
    const u16* b1p  = BtH + (size_t)(lr + 32) * 3008 + kg * 8;
    f32x16 acc0 = fzero16(), acc1 = fzero16();
    #pragma unroll 4
    for (int s = w; s < 188; s += 8) {
        int kk = s * 16;
        bf16x8 a;
        if (kk + kg * 8 < FIN) a = *(const bf16x8*)(arow + kk);
        else                   a = bzero8();
        bf16x8 b0 = *(const bf16x8*)(b0p + kk);   // Bt zero-padded to 3008
        bf16x8 b1 = *(const bf16x8*)(b1p + kk);
        acc0 = __builtin_amdgcn_mfma_f32_32x32x16_bf16(a, b0, acc0, 0, 0, 0);
        acc1 = __builtin_amdgcn_mfma_f32_32x32x16_bf16(a, b1, acc1, 0, 0, 0);
    }
    __shared__ float red[8][2048];         // 64 KB: per-wave 32x64 partials
    float* rp = red[w];
    #pragma unroll
    for (int reg = 0; reg < 16; reg++) {
        int row = (reg & 3) + 8 * (reg >> 2) + 4 * kg;
        rp[row * 64 + lr] = acc0[reg];
    }
    #pragma unroll
    for (int reg = 0; reg < 16; reg++) {
        int row = (reg & 3) + 8 * (reg >> 2) + 4 * kg;
        rp[row * 64 + 32 + lr] = acc1[reg];
    }
    __syncthreads();
    for (int i = tid; i < 2048; i += 512) {
        float s0 = 0.f;
        #pragma unroll
        for (int j = 0; j < 8; j++) s0 += red[j][i];
        X[(size_t)r0 * 64 + i] = s0;
    }
}

// ---- f32-input path: X = feat @ weight1 via split-bf16 3-term MFMA ----
// Round-6 structure (rounds 3-5 post-mortem: VGPR-level load pipelining is
// always defeated by the compiler -> use global_load_lds async DMA, which
// consumes no VGPRs and stays in flight until the barrier drain; m97 pattern):
//  * block 256 thr = 4 waves (2x2), tile 64 rows x 64 cols, K-chunk = 12 steps
//    of 64 k; grid (64, 2 feats, 4 K-chunks) = 512 blocks.
//  * per step: stage NEXT A-tile (64x64 f32, 16 KB) via 4 global_load_lds
//    width-16 per wave || compute CURRENT from LDS; one __syncthreads per step
//    (its vmcnt/lgkmcnt drain is the pipeline sync).
//  * LDS A-tile swizzled: byte (row*256 + (off ^ ((row&15)<<4))) -- breaks the
//    32-way bank conflict of row-major [64][64 f32]; applied on the global
//    SOURCE address (gload_lds writes linearly) and on the ds_read address.
//  * wave owns one 32x32 output tile; 4-way K-chunk reduce via atomicAdd.
//  * K-tail: A reads k in [3000,3008) are garbage but Bt rows are zero-padded
//    there, so the products vanish. (Last row reads 32 B past feat end --
//    within allocation granularity.)
__global__ __launch_bounds__(256) void k_featgemm_mfma_f32(const int* __restrict__ flag,
    const void* __restrict__ F0v, const void* __restrict__ F1v,
    const u16* __restrict__ BtH, const u16* __restrict__ BtL,
    float* __restrict__ X0, float* __restrict__ X1)
{
    if (!*flag) return;                    // bf16 mode: handled by k_featgemm_mfma
    const float* F = (const float*)(blockIdx.y ? F1v : F0v);
    float* X = blockIdx.y ? X1 : X0;
    int tid = threadIdx.x;
    int w  = tid >> 6;                     // wave id
    int l  = tid & 63;
    int lr = l & 31;
    int kg = l >> 5;                       // k-group (0..1), 8 elems each
    int wr = w >> 1, wc = w & 1;           // 2x2 wave grid
    int r0 = blockIdx.x * 64;
    int chunk = blockIdx.z;                // 0..3
    int sbeg = chunk * 12;
    int nsteps = ((chunk == 3) ? 47 : sbeg + 12) - sbeg;   // 12,12,12,11

    __shared__ char lds[2][16384];         // 2 x A[64 rows][64 k] f32, swizzled

    const float* Fb = F + (size_t)r0 * FIN;
    int arow = 32 * wr + lr;               // LDS row this lane reads
    int acol = 32 * wc + lr;               // B col = output col
    const u16* bh = BtH + (size_t)acol * 3008;
    const u16* bl = BtL + (size_t)acol * 3008;

    // per-lane staging geometry (wave w stages rows w*16..w*16+16)
    int slin = (w * 16) * 256 + l * 16;    // linear LDS byte of lane's first 16B
    f32x16 acc = fzero16();

    // prologue: stage step sbeg into buf 0
    {
        int kbase = sbeg * 64;
        #pragma unroll
        for (int j = 0; j < 4; j++) {
            int lin = slin + j * 1024;
            int row = lin >> 8;
            int off = (lin & 255) ^ ((row & 15) << 4);
            gload_lds16(Fb + (size_t)row * FIN + kbase + (off >> 2),
                        &lds[0][(w * 16 + j * 4) * 256]);
        }
    }
    __syncthreads();

    int cur = 0;
    for (int s = 0; s < nsteps; ++s) {
        if (s + 1 < nsteps) {              // stage next (wave-uniform guard)
            int kbase = (sbeg + s + 1) * 64;
            #pragma unroll
            for (int j = 0; j < 4; j++) {
                int lin = slin + j * 1024;
                int row = lin >> 8;
                int off = (lin & 255) ^ ((row & 15) << 4);
                gload_lds16(Fb + (size_t)row * FIN + kbase + (off >> 2),
                            &lds[cur ^ 1][(w * 16 + j * 4) * 256]);
            }
        }
        const char* lb = lds[cur];
        int kk0 = (sbeg + s) * 64;
        #pragma unroll
        for (int s16 = 0; s16 < 4; s16++) {
            int offu = s16 * 64 + kg * 32;
            int o0 = offu        ^ ((arow & 15) << 4);
            int o1 = (offu + 16) ^ ((arow & 15) << 4);
            float4 a0 = *(const float4*)(lb + arow * 256 + o0);
            float4 a1 = *(const float4*)(lb + arow * 256 + o1);
            float av[8] = {a0.x, a0.y, a0.z, a0.w, a1.x, a1.y, a1.z, a1.w};
            bf16x8 ah, al;
            #pragma unroll
            for (int jj = 0; jj < 8; jj++) {
                __bf16 hv = (__bf16)av[jj];
                ah[jj] = hv;
                al[jj] = (__bf16)(av[jj] - (float)hv);   // exact residual
            }
            int kk = kk0 + s16 * 16 + kg * 8;
            bf16x8 H = *(const bf16x8*)(bh + kk);
            bf16x8 L = *(const bf16x8*)(bl + kk);
            acc = __builtin_amdgcn_mfma_f32_32x32x16_bf16(ah, H, acc, 0, 0, 0);
            acc = __builtin_amdgcn_mfma_f32_32x32x16_bf16(al, H, acc, 0, 0, 0);
            acc = __builtin_amdgcn_mfma_f32_32x32x16_bf16(ah, L, acc, 0, 0, 0);
        }
        __syncthreads();                   // drains gload_lds (vmcnt) + ds reads
        cur ^= 1;
    }

    // 4-way K-chunk reduce (X pre-zeroed; 16 MB total atomic traffic)
    #pragma unroll
    for (int reg = 0; reg < 16; reg++) {
        int row = (reg & 3) + 8 * (reg >> 2) + 4 * kg;
        atomicAdd(&X[(size_t)(r0 + 32 * wr + row) * 64 + acol], acc[reg]);
    }
}

// ---- Wh = X @ att_W; s = Wh@a_src; d = Wh@a_dst (all-f32) ----
__global__ __launch_bounds__(64) void k_whsd(
    const float* __restrict__ X1, const float* __restrict__ X2,
    const float* __restrict__ AW, const float* __restrict__ asrc, const float* __restrict__ adst,
    float* __restrict__ Wh1, float* __restrict__ Wh2,
    float* __restrict__ s1, float* __restrict__ s2,
    float* __restrict__ d1, float* __restrict__ d2)
{
    const float* X = blockIdx.y ? X2 : X1;
    float* Wh = blockIdx.y ? Wh2 : Wh1;
    float* sv = blockIdx.y ? s2 : s1;
    float* dv = blockIdx.y ? d2 : d1;
    int row = blockIdx.x, c = threadIdx.x;
    __shared__ float x[64];
    x[c] = X[(size_t)row * 64 + c];
    __syncthreads();
    float acc = 0.f;
    #pragma unroll 16
    for (int k = 0; k < 64; k++) acc += x[k] * AW[k * 64 + c];
    Wh[(size_t)row * 64 + c] = acc;
    float vs = acc * asrc[c];
    float vd = acc * adst[c];
    #pragma unroll
    for (int off = 32; off > 0; off >>= 1) { vs += __shfl_down(vs, off); vd += __shfl_down(vd, off); }
    if (c == 0) { sv[row] = vs; dv[row] = vd; }
}

// ---- masked softmax (rank-1 scores) + P @ Wh over CSR neighbors ----
__global__ __launch_bounds__(128) void k_attn(
    const int* __restrict__ cnt, const int* __restrict__ idx,
    const float* __restrict__ s1, const float* __restrict__ s2,
    const float* __restrict__ d1, const float* __restrict__ d2,
    const float* __restrict__ Wh1, const float* __restrict__ Wh2,
    float* __restrict__ A1, float* __restrict__ A2)
{
    const float* sp = blockIdx.y ? s2 : s1;
    const float* dp = blockIdx.y ? d2 : d1;
    const float* Wh = blockIdx.y ? Wh2 : Wh1;
    float* A = blockIdx.y ? A2 : A1;
    int row = blockIdx.x, tid = threadIdx.x;
    int n = cnt[row];
    __shared__ int js[MAXN];
    __shared__ float ps[MAXN];
    __shared__ float red2[2];
    __shared__ float ared[2][64];
    for (int k = tid; k < n; k += 128) js[k] = idx[(size_t)row * MAXN + k];
    __syncthreads();
    float si = sp[row];
    float m = -3.0e38f;
    for (int k = tid; k < n; k += 128) {
        float e = si + dp[js[k]];
        e = e > 0.f ? e : 0.2f * e;   // LeakyReLU(0.2)
        ps[k] = e;
        m = fmaxf(m, e);
    }
    #pragma unroll
    for (int off = 32; off > 0; off >>= 1) m = fmaxf(m, __shfl_down(m, off));
    if ((tid & 63) == 0) red2[tid >> 6] = m;
    __syncthreads();
    m = fmaxf(red2[0], red2[1]);
    __syncthreads();
    float zz = 0.f;
    for (int k = tid; k < n; k += 128) {
        float p = __expf(ps[k] - m);
        ps[k] = p;
        zz += p;
    }
    #pragma unroll
    for (int off = 32; off > 0; off >>= 1) zz += __shfl_down(zz, off);
    if ((tid & 63) == 0) red2[tid >> 6] = zz;
    __syncthreads();
    float Z = red2[0] + red2[1];
    Z = fmaxf(Z, 1e-20f);           // guard 0/0
    int f = tid & 63, half = tid >> 6;
    float acc = 0.f;
    for (int k = half; k < n; k += 2) acc += ps[k] * Wh[(size_t)js[k] * 64 + f];
    ared[half][f] = acc;
    __syncthreads();
    if (tid < 64) A[(size_t)row * 64 + f] = (ared[0][f] + ared[1][f]) / Z;
}

// ---- 3-layer MLP 64->256->128->64; 4 rows/block; writes z (f32) and hiden_emb (dual-dtype, y==0) ----
__global__ __launch_bounds__(256) void k_mlp(const int* __restrict__ flag,
    const float* __restrict__ A1, const float* __restrict__ A2,
    const float* __restrict__ W1, const float* __restrict__ b1,
    const float* __restrict__ W2, const float* __restrict__ b2,
    const float* __restrict__ W3, const float* __restrict__ b3,
    float* __restrict__ Z1, float* __restrict__ Z2, void* __restrict__ hidenv)
{
    const float* A = blockIdx.y ? A2 : A1;
    float* Z = blockIdx.y ? Z2 : Z1;
    int row0 = blockIdx.x * 4, tid = threadIdx.x;
    __shared__ float x[4][64], h1[4][256], h2[4][128];
    {
        int r = tid >> 6, c = tid & 63;
        x[r][c] = A[(size_t)(row0 + r) * 64 + c];
    }
    __syncthreads();
    {
        float a0 = b1[tid], a1v = a0, a2v = a0, a3v = a0;
        #pragma unroll 8
        for (int k = 0; k < 64; k++) {
            float w = W1[k * 256 + tid];
            a0 += x[0][k] * w; a1v += x[1][k] * w; a2v += x[2][k] * w; a3v += x[3][k] * w;
        }
        h1[0][tid] = fmaxf(a0, 0.f);  h1[1][tid] = fmaxf(a1v, 0.f);
        h1[2][tid] = fmaxf(a2v, 0.f); h1[3][tid] = fmaxf(a3v, 0.f);
    }
    __syncthreads();
    if (tid < 128) {
        float a0 = b2[tid], a1v = a0, a2v = a0, a3v = a0;
        #pragma unroll 8
        for (int k = 0; k < 256; k++) {
            float w = W2[k * 128 + tid];
            a0 += h1[0][k] * w; a1v += h1[1][k] * w; a2v += h1[2][k] * w; a3v += h1[3][k] * w;
        }
        h2[0][tid] = fmaxf(a0, 0.f);  h2[1][tid] = fmaxf(a1v, 0.f);
        h2[2][tid] = fmaxf(a2v, 0.f); h2[3][tid] = fmaxf(a3v, 0.f);
    }
    __syncthreads();
    if (tid < 64) {
        float a[4];
        a[0] = a[1] = a[2] = a[3] = b3[tid];
        #pragma unroll 8
        for (int k = 0; k < 128; k++) {
            float w = W3[k * 64 + tid];
            a[0] += h2[0][k] * w; a[1] += h2[1][k] * w; a[2] += h2[2][k] * w; a[3] += h2[3][k] * w;
        }
        bool isf = (*flag != 0);
        #pragma unroll
        for (int r = 0; r < 4; r++) {
            size_t ei = (size_t)(row0 + r) * 64 + tid;
            Z[ei] = a[r];
            if (blockIdx.y == 0) {
                if (isf) ((float*)hidenv)[ei] = a[r];
                else     ((u16*)hidenv)[ei] = f2bf(a[r]);
            }
        }
    }
}

// ---- T = adj @ z over CSR ----
__global__ __launch_bounds__(64) void k_spmm(
    const int* __restrict__ cnt, const int* __restrict__ idx,
    const float* __restrict__ Z, float* __restrict__ T)
{
    int row = blockIdx.x, f = threadIdx.x;
    int n = cnt[row];
    const int* ir = idx + (size_t)row * MAXN;
    float acc = 0.f;
    for (int k = 0; k < n; k++) acc += Z[(size_t)ir[k] * 64 + f];
    T[(size_t)row * 64 + f] = acc;
}

// ---- H = T @ weight2 via split-bf16 3-term MFMA -> out (dual-dtype store) ----
__global__ __launch_bounds__(256) void k_hgemm_mfma(const int* __restrict__ flag,
    const float* __restrict__ T, const u16* __restrict__ WH, const u16* __restrict__ WL,
    void* __restrict__ outv)
{
    bool isf = (*flag != 0);
    int tid = threadIdx.x;
    int w = tid >> 6, l = tid & 63, lr = l & 31, kg = l >> 5;
    int ct = blockIdx.y * 4 + w;
    if (ct >= 94) return;                  // wave-uniform; no barriers in kernel
    int r0 = blockIdx.x * 32, c0 = ct * 32;
    const float* tp = T + (size_t)(r0 + lr) * 64 + kg * 8;
    bf16x8 ah[4], al[4];
    #pragma unroll
    for (int s = 0; s < 4; s++) {
        float4 p0 = *(const float4*)(tp + s * 16);
        float4 p1 = *(const float4*)(tp + s * 16 + 4);
        float av[8] = {p0.x, p0.y, p0.z, p0.w, p1.x, p1.y, p1.z, p1.w};
        #pragma unroll
        for (int j = 0; j < 8; j++) {
            __bf16 hv = (__bf16)av[j];
            ah[s][j] = hv;
            al[s][j] = (__bf16)(av[j] - (float)hv);   // exact residual
        }
    }
    const u16* bh = WH + (size_t)(c0 + lr) * 64 + kg * 8;
    const u16* bl = WL + (size_t)(c0 + lr) * 64 + kg * 8;
    f32x16 acc = fzero16();
    #pragma unroll
    for (int s = 0; s < 4; s++) {
        bf16x8 vh = *(const bf16x8*)(bh + s * 16);
        bf16x8 vl = *(const bf16x8*)(bl + s * 16);
        acc = __builtin_amdgcn_mfma_f32_32x32x16_bf16(ah[s], vh, acc, 0, 0, 0);
        acc = __builtin_amdgcn_mfma_f32_32x32x16_bf16(al[s], vh, acc, 0, 0, 0);
        acc = __builtin_amdgcn_mfma_f32_32x32x16_bf16(ah[s], vl, acc, 0, 0, 0);
    }
    int col = c0 + lr;
    bool cok = col < FIN;
    #pragma unroll
    for (int reg = 0; reg < 16; reg++) {
        int row = (reg & 3) + 8 * (reg >> 2) + 4 * kg;
        size_t ei = 262144 + (size_t)(r0 + row) * FIN + col;
        if (cok) {
            if (isf) ((float*)outv)[ei] = acc[reg];
            else     ((u16*)outv)[ei] = f2bf(acc[reg]);
        }
    }
}

// ---- readout: mean over graph_neigh nbrs of relu(z), L2 normalize, sigmoid ----
__global__ __launch_bounds__(64) void k_readout(
    const int* __restrict__ cnt, const int* __restrict__ idx,
    const float* __restrict__ Z1, const float* __restrict__ Z2,
    float* __restrict__ G1, float* __restrict__ G2)
{
    const float* Z = blockIdx.y ? Z2 : Z1;
    float* G = blockIdx.y ? G2 : G1;
    int row = blockIdx.x, f = threadIdx.x;
    int n = cnt[row];
    const int* ir = idx + (size_t)row * MAXN;
    float acc = 0.f;
    for (int k = 0; k < n; k++) acc += fmaxf(Z[(size_t)ir[k] * 64 + f], 0.f);
    acc /= (float)(n > 0 ? n : 1);
    float sq = acc * acc;
    #pragma unroll
    for (int off = 32; off > 0; off >>= 1) sq += __shfl_down(sq, off);
    sq = __shfl(sq, 0);
    float nrm = fmaxf(sqrtf(sq), 1e-12f);
    float v = acc / nrm;
    G[(size_t)row * 64 + f] = 1.f / (1.f + __expf(-v));
}

// ---- discriminator MLP 64->128->64; 4 rows/block; on {relu(z), relu(z_a), g, g_a} ----
__global__ __launch_bounds__(128) void k_dmlp(
    const float* __restrict__ z, const float* __restrict__ za,
    const float* __restrict__ g, const float* __restrict__ ga,
    const float* __restrict__ W1, const float* __restrict__ b1,
    const float* __restrict__ W2, const float* __restrict__ b2,
    float* __restrict__ De, float* __restrict__ Dea,
    float* __restrict__ Dg, float* __restrict__ Dga)
{
    int w = blockIdx.y;
    const float* X = (w == 0) ? z : (w == 1) ? za : (w == 2) ? g : ga;
    float* O = (w == 0) ? De : (w == 1) ? Dea : (w == 2) ? Dg : Dga;
    int doRelu = (w < 2);
    int row0 = blockIdx.x * 4, tid = threadIdx.x;
    __shared__ float x[4][64], h1[4][128];
    for (int i = tid; i < 256; i += 128) {
        int r = i >> 6, c = i & 63;
        float v = X[(size_t)(row0 + r) * 64 + c];
        x[r][c] = doRelu ? fmaxf(v, 0.f) : v;
    }
    __syncthreads();
    {
        float a0 = b1[tid], a1v = a0, a2v = a0, a3v = a0;
        #pragma unroll 8
        for (int k = 0; k < 64; k++) {
            float w_ = W1[k * 128 + tid];
            a0 += x[0][k] * w_; a1v += x[1][k] * w_; a2v += x[2][k] * w_; a3v += x[3][k] * w_;
        }
        h1[0][tid] = fmaxf(a0, 0.f);  h1[1][tid] = fmaxf(a1v, 0.f);
        h1[2][tid] = fmaxf(a2v, 0.f); h1[3][tid] = fmaxf(a3v, 0.f);
    }
    __syncthreads();
    if (tid < 64) {
        float a[4];
        a[0] = a[1] = a[2] = a[3] = b2[tid];
        #pragma unroll 8
        for (int k = 0; k < 128; k++) {
            float w_ = W2[k * 64 + tid];
            a[0] += h1[0][k] * w_; a[1] += h1[1][k] * w_; a[2] += h1[2][k] * w_; a[3] += h1[3][k] * w_;
        }
        #pragma unroll
        for (int r = 0; r < 4; r++) O[(size_t)(row0 + r) * 64 + tid] = a[r];
    }
}

// ---- bilinear: out = x . (bil_W @ y) + b ; dual-dtype store ----
__global__ __launch_bounds__(64) void k_bilin(const int* __restrict__ flag,
    const float* __restrict__ De, const float* __restrict__ Dea,
    const float* __restrict__ Dg, const float* __restrict__ Dga,
    const float* __restrict__ BW, const float* __restrict__ bb, void* __restrict__ outv)
{
    int w = blockIdx.y;
    const float* X = (w == 0 || w == 3) ? De : Dea;
    const float* Y = (w <= 1) ? Dg : Dga;
    size_t bse = (w <= 1) ? (size_t)12550144 : (size_t)12558336;
    int col = (w == 0 || w == 2) ? 0 : 1;
    int row = blockIdx.x, k = threadIdx.x;
    __shared__ float x[64], y[64];
    x[k] = X[(size_t)row * 64 + k];
    y[k] = Y[(size_t)row * 64 + k];
    __syncthreads();
    float wv = 0.f;
    #pragma unroll 8
    for (int j = 0; j < 64; j++) wv += BW[k * 64 + j] * y[j];
    float v = x[k] * wv;
    #pragma unroll
    for (int off = 32; off > 0; off >>= 1) v += __shfl_down(v, off);
    if (k == 0) {
        float r = v + bb[0];
        size_t ei = bse + (size_t)row * 2 + col;
        if (*flag) ((float*)outv)[ei] = r;
        else       ((u16*)outv)[ei] = f2bf(r);
    }
}

extern "C" void kernel_launch(void* const* d_in, const int* in_sizes, int n_in,
                              void* d_out, int out_size, void* d_ws, size_t ws_size,
                              hipStream_t stream) {
    const void* feat   = d_in[0];
    const void* feat_a = d_in[1];
    const void* adj    = d_in[2];
    const void* gn     = d_in[3];
    const void* w1     = d_in[4];
    const void* w2     = d_in[5];
    const void* attW   = d_in[6];
    const void* a_src  = d_in[7];
    const void* a_dst  = d_in[8];
    const void* mW1    = d_in[9];
    const void* mb1    = d_in[10];
    const void* mW2    = d_in[11];
    const void* mb2    = d_in[12];
    const void* mW3    = d_in[13];
    const void* mb3    = d_in[14];
    const void* dW1    = d_in[15];
    const void* db1    = d_in[16];
    const void* dW2    = d_in[17];
    const void* db2    = d_in[18];
    const void* bW     = d_in[19];
    const void* bb     = d_in[20];
    (void)in_sizes; (void)n_in; (void)out_size;

    // ---- d_ws: flag + T + W2tH/W2tL (~1.82 MB total) ----
    char* wsb = (char*)d_ws;
    int*   flag = (int*)wsb;                        // 4 B (pad 256)
    float* T    = (float*)(wsb + 256);              // 1,048,576 B
    u16*   W2tH = (u16*)(wsb + 256 + 1048576);      // 385,024 B
    u16*   W2tL = W2tH + 3008 * 64;                 // 385,024 B
    (void)ws_size;

    // ---- scratch arena at dtype-independent byte window of d_out:
    // bytes [1,048,576 , 21,200,000) lie inside the h output region for BOTH
    // bf16 (h bytes [524288,25100288)) and f32 (h bytes [1048576,50200576)),
    // and are fully overwritten by k_hgemm_mfma at the end.
    char* sc = (char*)d_out + 1048576;
    size_t soff = 0;
    auto salloc = [&](size_t nbytes) -> void* {
        void* p = (void*)(sc + soff);
        soff += (nbytes + 255) & ~(size_t)255;
        return p;
    };
    const size_t NV = (size_t)NN * 64;
    float* wA   = (float*)salloc((size_t)274689 * 4);  // 16-segment f32 weight arena
    int*   aCnt = (int*)salloc(NN * 4);
    int*   gCnt = (int*)salloc(NN * 4);
    int*   aIdx = (int*)salloc((size_t)NN * MAXN * 4);
    int*   gIdx = (int*)salloc((size_t)NN * MAXN * 4);
    float* X1  = (float*)salloc(NV * 4);
    float* X2  = (float*)salloc(NV * 4);   // contiguous with X1 (NV*4 is 256-mult)
    float* Wh1 = (float*)salloc(NV * 4);
    float* Wh2 = (float*)salloc(NV * 4);
    float* A1  = (float*)salloc(NV * 4);
    float* A2  = (float*)salloc(NV * 4);
    float* z   = (float*)salloc(NV * 4);
    float* za  = (float*)salloc(NV * 4);
    float* g   = (float*)salloc(NV * 4);
    float* ga  = (float*)salloc(NV * 4);
    float* De  = (float*)salloc(NV * 4);
    float* Dea = (float*)salloc(NV * 4);
    float* Dg  = (float*)salloc(NV * 4);
    float* Dga = (float*)salloc(NV * 4);
    float* s1  = (float*)salloc(NN * 4);
    float* s2  = (float*)salloc(NN * 4);
    float* d1  = (float*)salloc(NN * 4);
    float* d2  = (float*)salloc(NN * 4);
    // soff ~= 20.1 MB < 20.15 MB window: fits.

    float* w1f   = wA + 0;
    float* attWf = wA + 192000;
    float* asrcf = wA + 196096;
    float* adstf = wA + 196160;
    float* mW1f  = wA + 196224;
    float* mb1f  = wA + 212608;
    float* mW2f  = wA + 212864;
    float* mb2f  = wA + 245632;
    float* mW3f  = wA + 245760;
    float* mb3f  = wA + 253952;
    float* dW1f  = wA + 254016;
    float* db1f  = wA + 262208;
    float* dW2f  = wA + 262336;
    float* db2f  = wA + 270528;
    float* bWf   = wA + 270592;
    float* bbf   = wA + 274688;

    // BtH/BtL (split-bf16 W1^T [64][3008], 385 KB each) park in the De/Dea
    // slots: those are not written until k_dmlp, long after the feat GEMM.
    u16* BtH = (u16*)De;
    u16* BtL = (u16*)Dea;

    k_detect<<<1, 1024, 0, stream>>>((const u16*)feat, flag);
    k_convw<<<dim3(750, 16), 256, 0, stream>>>(flag,
        w1, attW, a_src, a_dst, mW1, mb1, mW2, mb2, mW3, mb3,
        dW1, db1, dW2, db2, bW, bb, wA);
    k_convw2t<<<752, 256, 0, stream>>>(flag, w2, W2tH, W2tL);
    k_convw1t<<<752, 256, 0, stream>>>(flag, w1, BtH, BtL);
    k_build_csr<<<dim3(NN, 2), 256, 0, stream>>>(flag, adj, gn, aCnt, aIdx, gCnt, gIdx);
    hipMemsetAsync(X1, 0, 2 * NV * 4, stream);   // zero X1+X2 for f32 K-split atomics
    k_featgemm_mfma<<<dim3(NN / 32, 2), 512, 0, stream>>>(flag, feat, feat_a, BtH, X1, X2);
    k_featgemm_mfma_f32<<<dim3(NN / 64, 2, 4), 256, 0, stream>>>(flag, feat, feat_a, BtH, BtL, X1, X2);
    k_whsd<<<dim3(NN, 2), 64, 0, stream>>>(X1, X2, attWf, asrcf, adstf, Wh1, Wh2, s1, s2, d1, d2);
    k_attn<<<dim3(NN, 2), 128, 0, stream>>>(aCnt, aIdx, s1, s2, d1, d2, Wh1, Wh2, A1, A2);
    k_mlp<<<dim3(NN / 4, 2), 256, 0, stream>>>(flag, A1, A2, mW1f, mb1f, mW2f, mb2f, mW3f, mb3f, z, za, d_out);
    k_readout<<<dim3(NN, 2), 64, 0, stream>>>(gCnt, gIdx, z, za, g, ga);
    k_dmlp<<<dim3(NN / 4, 4), 128, 0, stream>>>(z, za, g, ga, dW1f, db1f, dW2f, db2f, De, Dea, Dg, Dga);
    k_bilin<<<dim3(NN, 4), 64, 0, stream>>>(flag, De, Dea, Dg, Dga, bWf, bbf, d_out);
    k_spmm<<<NN, 64, 0, stream>>>(aCnt, aIdx, z, T);
    k_hgemm_mfma<<<dim3(NN / 32, 24), 256, 0, stream>>>(flag, T, W2tH, W2tL, d_out);
}

// Round 7
// 448.945 us; speedup vs baseline: 1.0715x; 1.0282x over previous
//
#include <hip/hip_runtime.h>

#define NN   4096
#define FIN  3000
#define MAXN 128

typedef unsigned short u16;
typedef __bf16 bf16x8 __attribute__((ext_vector_type(8)));
typedef float f32x16 __attribute__((ext_vector_type(16)));

__device__ __forceinline__ float bf2f(u16 u) { union { unsigned int i; float f; } v; v.i = ((unsigned int)u) << 16; return v.f; }
__device__ __forceinline__ u16 f2bf(float f) {
    union { float f; unsigned int i; } v; v.f = f;
    return (u16)((v.i + 0x7FFFu + ((v.i >> 16) & 1u)) >> 16);
}
__device__ __forceinline__ bf16x8 bzero8() {
    union { unsigned long long q[2]; bf16x8 v; } u; u.q[0] = 0ull; u.q[1] = 0ull; return u.v;
}
__device__ __forceinline__ f32x16 fzero16() {
    f32x16 v;
    #pragma unroll
    for (int i = 0; i < 16; i++) v[i] = 0.f;
    return v;
}
// async global->LDS, 16B per lane; dest = ldsbase + lane*16 (HW-fixed layout)
__device__ __forceinline__ void gload_lds16(const float* src, void* ldsbase) {
    __builtin_amdgcn_global_load_lds(
        (const __attribute__((address_space(1))) void*)src,
        (__attribute__((address_space(3))) void*)ldsbase, 16, 0, 0);
}

// ---- dtype detector: bf16 N(0,1) u16s have exponent ~127; f32-as-u16 halves are random.
__global__ __launch_bounds__(1024) void k_detect(const u16* __restrict__ feat, int* __restrict__ flag)
{
    __shared__ int tot;
    if (threadIdx.x == 0) tot = 0;
    __syncthreads();
    int ins = 0;
    for (int i = threadIdx.x; i < 16384; i += 1024) {
        u16 u = feat[i];
        int e = (u >> 7) & 0xFF;
        if (u != 0 && (e < 90 || e > 160)) ins++;
    }
    atomicAdd(&tot, ins);
    __syncthreads();
    if (threadIdx.x == 0) *flag = (tot > 1024) ? 1 : 0;   // 1 = inputs are f32
}

// ---- convert 16 weight tensors -> f32 arena (blockIdx.y = segment) ----
__global__ __launch_bounds__(256) void k_convw(const int* __restrict__ flag,
    const void* s0, const void* s1, const void* s2, const void* s3,
    const void* s4, const void* s5, const void* s6, const void* s7,
    const void* s8, const void* s9, const void* s10, const void* s11,
    const void* s12, const void* s13, const void* s14, const void* s15,
    float* __restrict__ dst)
{
    const void* srcs[16] = {s0,s1,s2,s3,s4,s5,s6,s7,s8,s9,s10,s11,s12,s13,s14,s15};
    const int offs[16] = {0,192000,196096,196160,196224,212608,212864,245632,245760,253952,254016,262208,262336,270528,270592,274688};
    const int ns[16]   = {192000,4096,64,64,16384,256,32768,128,8192,64,8192,128,8192,64,4096,1};
    int seg = blockIdx.y;
    int i = blockIdx.x * 256 + threadIdx.x;
    if (i >= ns[seg]) return;
    float v = (*flag) ? ((const float*)srcs[seg])[i] : bf2f(((const u16*)srcs[seg])[i]);
    dst[offs[seg] + i] = v;
}

// ---- build W2tH/W2tL = split-bf16 W2^T [3008][64] (n-major), zero-padded in n ----
__global__ __launch_bounds__(256) void k_convw2t(const int* __restrict__ flag,
    const void* __restrict__ src, u16* __restrict__ WH, u16* __restrict__ WL)
{
    int i = blockIdx.x * 256 + threadIdx.x;      // over 3008*64
    if (i >= 3008 * 64) return;
    int n = i >> 6, k = i & 63;
    float v = 0.f;
    if (n < FIN)
        v = (*flag) ? ((const float*)src)[(size_t)k * FIN + n]
                    : bf2f(((const u16*)src)[(size_t)k * FIN + n]);
    u16 h = f2bf(v);
    float r = v - bf2f(h);                       // exact in f32
    WH[i] = h;
    WL[i] = f2bf(r);
}

// ---- build BtH/BtL = split-bf16 W1^T [64][3008], zero-padded in k ----
__global__ __launch_bounds__(256) void k_convw1t(const int* __restrict__ flag,
    const void* __restrict__ w1src, u16* __restrict__ BtH, u16* __restrict__ BtL)
{
    int i = blockIdx.x * 256 + threadIdx.x;      // over 64*3008
    if (i >= 64 * 3008) return;
    int c = i / 3008, k = i - c * 3008;
    float v = 0.f;
    if (k < 3000)
        v = (*flag) ? ((const float*)w1src)[(size_t)k * 64 + c]
                    : bf2f(((const u16*)w1src)[(size_t)k * 64 + c]);
    u16 h = f2bf(v);
    float r = v - bf2f(h);                       // exact in f32
    BtH[(size_t)c * 3008 + k] = h;
    BtL[(size_t)c * 3008 + k] = f2bf(r);
}

// ---- ordered CSR build (prefix-scan, deterministic, sorted) for adj / graph_neigh ----
__global__ __launch_bounds__(256) void k_build_csr(const int* __restrict__ flag,
    const void* __restrict__ Av, const void* __restrict__ Gv,
    int* __restrict__ aCnt, int* __restrict__ aIdx,
    int* __restrict__ gCnt, int* __restrict__ gIdx)
{
    bool isf = (*flag != 0);
    const void* M = blockIdx.y ? Gv : Av;
    int* cnt = blockIdx.y ? gCnt : aCnt;
    int* idx = blockIdx.y ? gIdx : aIdx;
    int row = blockIdx.x, t = threadIdx.x;
    int c0 = t * 16;
    unsigned int mask = 0; int my = 0;
    if (isf) {
        const float4* r = (const float4*)((const float*)M + (size_t)row * NN + c0);
        union { float4 q[4]; float f[16]; } u;
        u.q[0] = r[0]; u.q[1] = r[1]; u.q[2] = r[2]; u.q[3] = r[3];
        #pragma unroll
        for (int j = 0; j < 16; j++) if (u.f[j] != 0.f) { mask |= 1u << j; my++; }
    } else {
        const uint4* r = (const uint4*)((const u16*)M + (size_t)row * NN + c0);
        union { uint4 q[2]; u16 h[16]; } u;
        u.q[0] = r[0]; u.q[1] = r[1];
        #pragma unroll
        for (int j = 0; j < 16; j++) if (u.h[j] != 0) { mask |= 1u << j; my++; }
    }
    __shared__ int sc[256];
    sc[t] = my;
    __syncthreads();
    for (int d = 1; d < 256; d <<= 1) {
        int v = (t >= d) ? sc[t - d] : 0;
        __syncthreads();
        sc[t] += v;
        __syncthreads();
    }
    int pos = sc[t] - my;
    for (int j = 0; j < 16; j++) {
        if (mask & (1u << j)) {
            if (pos < MAXN) idx[(size_t)row * MAXN + pos] = c0 + j;
            pos++;
        }
    }
    if (t == 0) { int total = sc[255]; cnt[row] = (total < MAXN) ? total : MAXN; }
}

// ---- bf16-input path: X = feat @ weight1 via 1-term v_mfma_f32_32x32x16_bf16 ----
__global__ __launch_bounds__(512) void k_featgemm_mfma(const int* __restrict__ flag,
    const void* __restrict__ F0v, const void* __restrict__ F1v,
    const u16* __restrict__ BtH, float* __restrict__ X0, float* __restrict__ X1)
{
    if (*flag) return;                     // f32 mode: handled by k_featgemm_mfma_f32
    const u16* F = (const u16*)(blockIdx.y ? F1v : F0v);
    float* X = blockIdx.y ? X1 : X0;
    int r0 = blockIdx.x * 32;
    int tid = threadIdx.x;
    int w  = tid >> 6;                     // wave id = K-eighth
    int l  = tid & 63;
    int lr = l & 31;                       // A row / B col / D col
    int kg = l >> 5;                       // k-group (0..1), 8 elems each
    const u16* arow = F   + (size_t)(r0 + lr) * FIN + kg * 8;
    const u16* b0p  = BtH + (size_t)lr * 3008 + kg * 8;
    const u16* b1p  = BtH + (size_t)(lr + 32) * 3008 + kg * 8;
    f32x16 acc0 = fzero16(), acc1 = fzero16();
    #pragma unroll 4
    for (int s = w; s < 188; s += 8) {
        int kk = s * 16;
        bf16x8 a;
        if (kk + kg * 8 < FIN) a = *(const bf16x8*)(arow + kk);
        else                   a = bzero8();
        bf16x8 b0 = *(const bf16x8*)(b0p + kk);   // Bt zero-padded to 3008
        bf16x8 b1 = *(const bf16x8*)(b1p + kk);
        acc0 = __builtin_amdgcn_mfma_f32_32x32x16_bf16(a, b0, acc0, 0, 0, 0);
        acc1 = __builtin_amdgcn_mfma_f32_32x32x16_bf16(a, b1, acc1, 0, 0, 0);
    }
    __shared__ float red[8][2048];         // 64 KB: per-wave 32x64 partials
    float* rp = red[w];
    #pragma unroll
    for (int reg = 0; reg < 16; reg++) {
        int row = (reg & 3) + 8 * (reg >> 2) + 4 * kg;
        rp[row * 64 + lr] = acc0[reg];
    }
    #pragma unroll
    for (int reg = 0; reg < 16; reg++) {
        int row = (reg & 3) + 8 * (reg >> 2) + 4 * kg;
        rp[row * 64 + 32 + lr] = acc1[reg];
    }
    __syncthreads();
    for (int i = tid; i < 2048; i += 512) {
        float s0 = 0.f;
        #pragma unroll
        for (int j = 0; j < 8; j++) s0 += red[j][i];
        X[(size_t)r0 * 64 + i] = s0;
    }
}

// ---- f32-input path: X = feat @ weight1 via split-bf16 3-term MFMA ----
// Round-7: counted-vmcnt pipeline (round-6 post-mortem: __syncthreads drains
// vmcnt(0) -> every step pays full stage latency; 5.2 us/step, all pipes idle).
//  * 3 LDS buffers (48 KB), stage distance 2: stage(s+2) issued right after the
//    step-s barrier; before reading buf(s) wait `s_waitcnt vmcnt(4)` (allow
//    stage(s+1)'s 4 ops in flight), vmcnt(0) only on the final step.
//  * raw s_barrier (no compiler drain). Safety: each wave counts its OWN stage
//    ops; barrier globalizes completion; step s-1 ds_reads are consumed
//    (lgkm-waited before their MFMAs) before any wave reaches the step-s
//    barrier, so overwriting buf((s+2)%3)=buf((s-1)%3) after it is race-free.
//  * geometry unchanged from round 6 (verified): 64x64 tile, 2x2 waves,
//    XOR-swizzled A staging, 4-way K-chunk atomicAdd reduce.
__global__ __launch_bounds__(256) void k_featgemm_mfma_f32(const int* __restrict__ flag,
    const void* __restrict__ F0v, const void* __restrict__ F1v,
    const u16* __restrict__ BtH, const u16* __restrict__ BtL,
    float* __restrict__ X0, float* __restrict__ X1)
{
    if (!*flag) return;                    // bf16 mode: handled by k_featgemm_mfma
    const float* F = (const float*)(blockIdx.y ? F1v : F0v);
    float* X = blockIdx.y ? X1 : X0;
    int tid = threadIdx.x;
    int w  = tid >> 6;                     // wave id
    int l  = tid & 63;
    int lr = l & 31;
    int kg = l >> 5;                       // k-group (0..1), 8 elems each
    int wr = w >> 1, wc = w & 1;           // 2x2 wave grid
    int r0 = blockIdx.x * 64;
    int chunk = blockIdx.z;                // 0..3
    int sbeg = chunk * 12;
    int nsteps = (chunk == 3) ? 11 : 12;

    __shared__ char lds[3][16384];         // 3 x A[64 rows][64 k] f32, swizzled

    const float* Fb = F + (size_t)r0 * FIN;
    int arow = 32 * wr + lr;               // LDS row this lane reads
    int acol = 32 * wc + lr;               // B col = output col
    const u16* bh = BtH + (size_t)acol * 3008;
    const u16* bl = BtL + (size_t)acol * 3008;
    int slin = (w * 16) * 256 + l * 16;    // linear LDS byte of lane's first 16B
    f32x16 acc = fzero16();

    auto STAGE = [&](int s, int buf) {
        int kbase = (sbeg + s) * 64;
        #pragma unroll
        for (int j = 0; j < 4; j++) {
            int lin = slin + j * 1024;
            int row = lin >> 8;
            int off = (lin & 255) ^ ((row & 15) << 4);
            gload_lds16(Fb + (size_t)row * FIN + kbase + (off >> 2),
                        &lds[buf][(w * 16 + j * 4) * 256]);
        }
    };

    STAGE(0, 0);
    STAGE(1, 1);

    for (int s = 0; s < nsteps; ++s) {
        if (s < nsteps - 1) asm volatile("s_waitcnt vmcnt(4)" ::: "memory");
        else                asm volatile("s_waitcnt vmcnt(0)" ::: "memory");
        __builtin_amdgcn_s_barrier();
        if (s + 2 < nsteps) STAGE(s + 2, (s + 2) % 3);
        const char* lb = lds[s % 3];
        int kk0 = (sbeg + s) * 64;
        #pragma unroll
        for (int s16 = 0; s16 < 4; s16++) {
            int offu = s16 * 64 + kg * 32;
            int o0 = offu        ^ ((arow & 15) << 4);
            int o1 = (offu + 16) ^ ((arow & 15) << 4);
            float4 a0 = *(const float4*)(lb + arow * 256 + o0);
            float4 a1 = *(const float4*)(lb + arow * 256 + o1);
            float av[8] = {a0.x, a0.y, a0.z, a0.w, a1.x, a1.y, a1.z, a1.w};
            bf16x8 ah, al;
            #pragma unroll
            for (int jj = 0; jj < 8; jj++) {
                __bf16 hv = (__bf16)av[jj];
                ah[jj] = hv;
                al[jj] = (__bf16)(av[jj] - (float)hv);   // exact residual
            }
            int kk = kk0 + s16 * 16 + kg * 8;
            bf16x8 H = *(const bf16x8*)(bh + kk);
            bf16x8 L = *(const bf16x8*)(bl + kk);
            acc = __builtin_amdgcn_mfma_f32_32x32x16_bf16(ah, H, acc, 0, 0, 0);
            acc = __builtin_amdgcn_mfma_f32_32x32x16_bf16(al, H, acc, 0, 0, 0);
            acc = __builtin_amdgcn_mfma_f32_32x32x16_bf16(ah, L, acc, 0, 0, 0);
        }
    }

    // 4-way K-chunk reduce (X pre-zeroed; L2-resident atomics)
    #pragma unroll
    for (int reg = 0; reg < 16; reg++) {
        int row = (reg & 3) + 8 * (reg >> 2) + 4 * kg;
        atomicAdd(&X[(size_t)(r0 + 32 * wr + row) * 64 + acol], acc[reg]);
    }
}

// ---- Wh = X @ att_W; s = Wh@a_src; d = Wh@a_dst; 4 rows/block, attW in LDS ----
__global__ __launch_bounds__(256) void k_whsd(
    const float* __restrict__ X1, const float* __restrict__ X2,
    const float* __restrict__ AW, const float* __restrict__ asrc, const float* __restrict__ adst,
    float* __restrict__ Wh1, float* __restrict__ Wh2,
    float* __restrict__ s1, float* __restrict__ s2,
    float* __restrict__ d1, float* __restrict__ d2)
{
    const float* X = blockIdx.y ? X2 : X1;
    float* Wh = blockIdx.y ? Wh2 : Wh1;
    float* sv = blockIdx.y ? s2 : s1;
    float* dv = blockIdx.y ? d2 : d1;
    __shared__ float aw[64][65];           // padded: bank (k+c)%32, 2-way free
    __shared__ float x[4][65];
    int tid = threadIdx.x;
    for (int i = tid; i < 4096; i += 256) aw[i >> 6][i & 63] = AW[i];
    int g = tid >> 6, c = tid & 63;
    int row = blockIdx.x * 4 + g;
    x[g][c] = X[(size_t)row * 64 + c];
    __syncthreads();
    float acc = 0.f;
    #pragma unroll 16
    for (int k = 0; k < 64; k++) acc += x[g][k] * aw[k][c];
    Wh[(size_t)row * 64 + c] = acc;
    float vs = acc * asrc[c];
    float vd = acc * adst[c];
    #pragma unroll
    for (int off = 32; off > 0; off >>= 1) { vs += __shfl_down(vs, off); vd += __shfl_down(vd, off); }
    if (c == 0) { sv[row] = vs; dv[row] = vd; }
}

// ---- masked softmax (rank-1 scores) + P @ Wh over CSR neighbors ----
__global__ __launch_bounds__(128) void k_attn(
    const int* __restrict__ cnt, const int* __restrict__ idx,
    const float* __restrict__ s1, const float* __restrict__ s2,
    const float* __restrict__ d1, const float* __restrict__ d2,
    const float* __restrict__ Wh1, const float* __restrict__ Wh2,
    float* __restrict__ A1, float* __restrict__ A2)
{
    const float* sp = blockIdx.y ? s2 : s1;
    const float* dp = blockIdx.y ? d2 : d1;
    const float* Wh = blockIdx.y ? Wh2 : Wh1;
    float* A = blockIdx.y ? A2 : A1;
    int row = blockIdx.x, tid = threadIdx.x;
    int n = cnt[row];
    __shared__ int js[MAXN];
    __shared__ float ps[MAXN];
    __shared__ float red2[2];
    __shared__ float ared[2][64];
    for (int k = tid; k < n; k += 128) js[k] = idx[(size_t)row * MAXN + k];
    __syncthreads();
    float si = sp[row];
    float m = -3.0e38f;
    for (int k = tid; k < n; k += 128) {
        float e = si + dp[js[k]];
        e = e > 0.f ? e : 0.2f * e;   // LeakyReLU(0.2)
        ps[k] = e;
        m = fmaxf(m, e);
    }
    #pragma unroll
    for (int off = 32; off > 0; off >>= 1) m = fmaxf(m, __shfl_down(m, off));
    if ((tid & 63) == 0) red2[tid >> 6] = m;
    __syncthreads();
    m = fmaxf(red2[0], red2[1]);
    __syncthreads();
    float zz = 0.f;
    for (int k = tid; k < n; k += 128) {
        float p = __expf(ps[k] - m);
        ps[k] = p;
        zz += p;
    }
    #pragma unroll
    for (int off = 32; off > 0; off >>= 1) zz += __shfl_down(zz, off);
    if ((tid & 63) == 0) red2[tid >> 6] = zz;
    __syncthreads();
    float Z = red2[0] + red2[1];
    Z = fmaxf(Z, 1e-20f);           // guard 0/0
    int f = tid & 63, half = tid >> 6;
    float acc = 0.f;
    for (int k = half; k < n; k += 2) acc += ps[k] * Wh[(size_t)js[k] * 64 + f];
    ared[half][f] = acc;
    __syncthreads();
    if (tid < 64) A[(size_t)row * 64 + f] = (ared[0][f] + ared[1][f]) / Z;
}

// ---- 3-layer MLP 64->256->128->64; 4 rows/block; writes z (f32) and hiden_emb (dual-dtype, y==0) ----
__global__ __launch_bounds__(256) void k_mlp(const int* __restrict__ flag,
    const float* __restrict__ A1, const float* __restrict__ A2,
    const float* __restrict__ W1, const float* __restrict__ b1,
    const float* __restrict__ W2, const float* __restrict__ b2,
    const float* __restrict__ W3, const float* __restrict__ b3,
    float* __restrict__ Z1, float* __restrict__ Z2, void* __restrict__ hidenv)
{
    const float* A = blockIdx.y ? A2 : A1;
    float* Z = blockIdx.y ? Z2 : Z1;
    int row0 = blockIdx.x * 4, tid = threadIdx.x;
    __shared__ float x[4][64], h1[4][256], h2[4][128];
    {
        int r = tid >> 6, c = tid & 63;
        x[r][c] = A[(size_t)(row0 + r) * 64 + c];
    }
    __syncthreads();
    {
        float a0 = b1[tid], a1v = a0, a2v = a0, a3v = a0;
        #pragma unroll 8
        for (int k = 0; k < 64; k++) {
            float w = W1[k * 256 + tid];
            a0 += x[0][k] * w; a1v += x[1][k] * w; a2v += x[2][k] * w; a3v += x[3][k] * w;
        }
        h1[0][tid] = fmaxf(a0, 0.f);  h1[1][tid] = fmaxf(a1v, 0.f);
        h1[2][tid] = fmaxf(a2v, 0.f); h1[3][tid] = fmaxf(a3v, 0.f);
    }
    __syncthreads();
    if (tid < 128) {
        float a0 = b2[tid], a1v = a0, a2v = a0, a3v = a0;
        #pragma unroll 8
        for (int k = 0; k < 256; k++) {
            float w = W2[k * 128 + tid];
            a0 += h1[0][k] * w; a1v += h1[1][k] * w; a2v += h1[2][k] * w; a3v += h1[3][k] * w;
        }
        h2[0][tid] = fmaxf(a0, 0.f);  h2[1][tid] = fmaxf(a1v, 0.f);
        h2[2][tid] = fmaxf(a2v, 0.f); h2[3][tid] = fmaxf(a3v, 0.f);
    }
    __syncthreads();
    if (tid < 64) {
        float a[4];
        a[0] = a[1] = a[2] = a[3] = b3[tid];
        #pragma unroll 8
        for (int k = 0; k < 128; k++) {
            float w = W3[k * 64 + tid];
            a[0] += h2[0][k] * w; a[1] += h2[1][k] * w; a[2] += h2[2][k] * w; a[3] += h2[3][k] * w;
        }
        bool isf = (*flag != 0);
        #pragma unroll
        for (int r = 0; r < 4; r++) {
            size_t ei = (size_t)(row0 + r) * 64 + tid;
            Z[ei] = a[r];
            if (blockIdx.y == 0) {
                if (isf) ((float*)hidenv)[ei] = a[r];
                else     ((u16*)hidenv)[ei] = f2bf(a[r]);
            }
        }
    }
}

// ---- T = adj @ z over CSR ----
__global__ __launch_bounds__(64) void k_spmm(
    const int* __restrict__ cnt, const int* __restrict__ idx,
    const float* __restrict__ Z, float* __restrict__ T)
{
    int row = blockIdx.x, f = threadIdx.x;
    int n = cnt[row];
    const int* ir = idx + (size_t)row * MAXN;
    float acc = 0.f;
    for (int k = 0; k < n; k++) acc += Z[(size_t)ir[k] * 64 + f];
    T[(size_t)row * 64 + f] = acc;
}

// ---- H = T @ weight2 via split-bf16 3-term MFMA -> out (dual-dtype store) ----
__global__ __launch_bounds__(256) void k_hgemm_mfma(const int* __restrict__ flag,
    const float* __restrict__ T, const u16* __restrict__ WH, const u16* __restrict__ WL,
    void* __restrict__ outv)
{
    bool isf = (*flag != 0);
    int tid = threadIdx.x;
    int w = tid >> 6, l = tid & 63, lr = l & 31, kg = l >> 5;
    int ct = blockIdx.y * 4 + w;
    if (ct >= 94) return;                  // wave-uniform; no barriers in kernel
    int r0 = blockIdx.x * 32, c0 = ct * 32;
    const float* tp = T + (size_t)(r0 + lr) * 64 + kg * 8;
    bf16x8 ah[4], al[4];
    #pragma unroll
    for (int s = 0; s < 4; s++) {
        float4 p0 = *(const float4*)(tp + s * 16);
        float4 p1 = *(const float4*)(tp + s * 16 + 4);
        float av[8] = {p0.x, p0.y, p0.z, p0.w, p1.x, p1.y, p1.z, p1.w};
        #pragma unroll
        for (int j = 0; j < 8; j++) {
            __bf16 hv = (__bf16)av[j];
            ah[s][j] = hv;
            al[s][j] = (__bf16)(av[j] - (float)hv);   // exact residual
        }
    }
    const u16* bh = WH + (size_t)(c0 + lr) * 64 + kg * 8;
    const u16* bl = WL + (size_t)(c0 + lr) * 64 + kg * 8;
    f32x16 acc = fzero16();
    #pragma unroll
    for (int s = 0; s < 4; s++) {
        bf16x8 vh = *(const bf16x8*)(bh + s * 16);
        bf16x8 vl = *(const bf16x8*)(bl + s * 16);
        acc = __builtin_amdgcn_mfma_f32_32x32x16_bf16(ah[s], vh, acc, 0, 0, 0);
        acc = __builtin_amdgcn_mfma_f32_32x32x16_bf16(al[s], vh, acc, 0, 0, 0);
        acc = __builtin_amdgcn_mfma_f32_32x32x16_bf16(ah[s], vl, acc, 0, 0, 0);
    }
    int col = c0 + lr;
    bool cok = col < FIN;
    #pragma unroll
    for (int reg = 0; reg < 16; reg++) {
        int row = (reg & 3) + 8 * (reg >> 2) + 4 * kg;
        size_t ei = 262144 + (size_t)(r0 + row) * FIN + col;
        if (cok) {
            if (isf) ((float*)outv)[ei] = acc[reg];
            else     ((u16*)outv)[ei] = f2bf(acc[reg]);
        }
    }
}

// ---- readout: mean over graph_neigh nbrs of relu(z), L2 normalize, sigmoid ----
__global__ __launch_bounds__(64) void k_readout(
    const int* __restrict__ cnt, const int* __restrict__ idx,
    const float* __restrict__ Z1, const float* __restrict__ Z2,
    float* __restrict__ G1, float* __restrict__ G2)
{
    const float* Z = blockIdx.y ? Z2 : Z1;
    float* G = blockIdx.y ? G2 : G1;
    int row = blockIdx.x, f = threadIdx.x;
    int n = cnt[row];
    const int* ir = idx + (size_t)row * MAXN;
    float acc = 0.f;
    for (int k = 0; k < n; k++) acc += fmaxf(Z[(size_t)ir[k] * 64 + f], 0.f);
    acc /= (float)(n > 0 ? n : 1);
    float sq = acc * acc;
    #pragma unroll
    for (int off = 32; off > 0; off >>= 1) sq += __shfl_down(sq, off);
    sq = __shfl(sq, 0);
    float nrm = fmaxf(sqrtf(sq), 1e-12f);
    float v = acc / nrm;
    G[(size_t)row * 64 + f] = 1.f / (1.f + __expf(-v));
}

// ---- discriminator MLP 64->128->64; 4 rows/block; on {relu(z), relu(z_a), g, g_a} ----
__global__ __launch_bounds__(128) void k_dmlp(
    const float* __restrict__ z, const float* __restrict__ za,
    const float* __restrict__ g, const float* __restrict__ ga,
    const float* __restrict__ W1, const float* __restrict__ b1,
    const float* __restrict__ W2, const float* __restrict__ b2,
    float* __restrict__ De, float* __restrict__ Dea,
    float* __restrict__ Dg, float* __restrict__ Dga)
{
    int w = blockIdx.y;
    const float* X = (w == 0) ? z : (w == 1) ? za : (w == 2) ? g : ga;
    float* O = (w == 0) ? De : (w == 1) ? Dea : (w == 2) ? Dg : Dga;
    int doRelu = (w < 2);
    int row0 = blockIdx.x * 4, tid = threadIdx.x;
    __shared__ float x[4][64], h1[4][128];
    for (int i = tid; i < 256; i += 128) {
        int r = i >> 6, c = i & 63;
        float v = X[(size_t)(row0 + r) * 64 + c];
        x[r][c] = doRelu ? fmaxf(v, 0.f) : v;
    }
    __syncthreads();
    {
        float a0 = b1[tid], a1v = a0, a2v = a0, a3v = a0;
        #pragma unroll 8
        for (int k = 0; k < 64; k++) {
            float w_ = W1[k * 128 + tid];
            a0 += x[0][k] * w_; a1v += x[1][k] * w_; a2v += x[2][k] * w_; a3v += x[3][k] * w_;
        }
        h1[0][tid] = fmaxf(a0, 0.f);  h1[1][tid] = fmaxf(a1v, 0.f);
        h1[2][tid] = fmaxf(a2v, 0.f); h1[3][tid] = fmaxf(a3v, 0.f);
    }
    __syncthreads();
    if (tid < 64) {
        float a[4];
        a[0] = a[1] = a[2] = a[3] = b2[tid];
        #pragma unroll 8
        for (int k = 0; k < 128; k++) {
            float w_ = W2[k * 64 + tid];
            a[0] += h1[0][k] * w_; a[1] += h1[1][k] * w_; a[2] += h1[2][k] * w_; a[3] += h1[3][k] * w_;
        }
        #pragma unroll
        for (int r = 0; r < 4; r++) O[(size_t)(row0 + r) * 64 + tid] = a[r];
    }
}

// ---- bilinear stage 1: V = Y @ BW^T for Y in {Dg, Dga}; BW cached in LDS ----
__global__ __launch_bounds__(256) void k_bilin_pre(
    const float* __restrict__ Dg, const float* __restrict__ Dga,
    const float* __restrict__ BW, float* __restrict__ V1, float* __restrict__ V2)
{
    const float* Y = blockIdx.y ? Dga : Dg;
    float* V = blockIdx.y ? V2 : V1;
    __shared__ float bw[64][65];           // padded
    __shared__ float y[4][65];
    int tid = threadIdx.x;
    for (int i = tid; i < 4096; i += 256) bw[i >> 6][i & 63] = BW[i];
    int g = tid >> 6, k = tid & 63;
    int rbase = blockIdx.x * 64;
    for (int it = 0; it < 16; it++) {
        __syncthreads();
        int r = rbase + it * 4 + g;
        y[g][k] = Y[(size_t)r * 64 + k];
        __syncthreads();
        float acc = 0.f;
        #pragma unroll 16
        for (int j = 0; j < 64; j++) acc += y[g][j] * bw[k][j];
        V[(size_t)r * 64 + k] = acc;       // V[r][k] = (BW @ y_r)[k]
    }
}

// ---- bilinear stage 2: out = dot(x_r, V_r) + b ; 4 rows/block, dual-dtype ----
__global__ __launch_bounds__(256) void k_bilin_dot(const int* __restrict__ flag,
    const float* __restrict__ De, const float* __restrict__ Dea,
    const float* __restrict__ V1, const float* __restrict__ V2,
    const float* __restrict__ bb, void* __restrict__ outv)
{
    int w = blockIdx.y;
    const float* X = (w == 0 || w == 3) ? De : Dea;
    const float* V = (w <= 1) ? V1 : V2;
    size_t bse = (w <= 1) ? (size_t)12550144 : (size_t)12558336;
    int col = (w == 0 || w == 2) ? 0 : 1;
    int g = threadIdx.x >> 6, k = threadIdx.x & 63;
    int row = blockIdx.x * 4 + g;
    float v = X[(size_t)row * 64 + k] * V[(size_t)row * 64 + k];
    #pragma unroll
    for (int off = 32; off > 0; off >>= 1) v += __shfl_down(v, off);
    if (k == 0) {
        float r = v + bb[0];
        size_t ei = bse + (size_t)row * 2 + col;
        if (*flag) ((float*)outv)[ei] = r;
        else       ((u16*)outv)[ei] = f2bf(r);
    }
}

extern "C" void kernel_launch(void* const* d_in, const int* in_sizes, int n_in,
                              void* d_out, int out_size, void* d_ws, size_t ws_size,
                              hipStream_t stream) {
    const void* feat   = d_in[0];
    const void* feat_a = d_in[1];
    const void* adj    = d_in[2];
    const void* gn     = d_in[3];
    const void* w1     = d_in[4];
    const void* w2     = d_in[5];
    const void* attW   = d_in[6];
    const void* a_src  = d_in[7];
    const void* a_dst  = d_in[8];
    const void* mW1    = d_in[9];
    const void* mb1    = d_in[10];
    const void* mW2    = d_in[11];
    const void* mb2    = d_in[12];
    const void* mW3    = d_in[13];
    const void* mb3    = d_in[14];
    const void* dW1    = d_in[15];
    const void* db1    = d_in[16];
    const void* dW2    = d_in[17];
    const void* db2    = d_in[18];
    const void* bW     = d_in[19];
    const void* bb     = d_in[20];
    (void)in_sizes; (void)n_in; (void)out_size;

    // ---- d_ws: flag + T + W2tH/W2tL (~1.82 MB total) ----
    char* wsb = (char*)d_ws;
    int*   flag = (int*)wsb;                        // 4 B (pad 256)
    float* T    = (float*)(wsb + 256);              // 1,048,576 B
    u16*   W2tH = (u16*)(wsb + 256 + 1048576);      // 385,024 B
    u16*   W2tL = W2tH + 3008 * 64;                 // 385,024 B
    (void)ws_size;

    // ---- scratch arena at dtype-independent byte window of d_out ----
    char* sc = (char*)d_out + 1048576;
    size_t soff = 0;
    auto salloc = [&](size_t nbytes) -> void* {
        void* p = (void*)(sc + soff);
        soff += (nbytes + 255) & ~(size_t)255;
        return p;
    };
    const size_t NV = (size_t)NN * 64;
    float* wA   = (float*)salloc((size_t)274689 * 4);  // 16-segment f32 weight arena
    int*   aCnt = (int*)salloc(NN * 4);
    int*   gCnt = (int*)salloc(NN * 4);
    int*   aIdx = (int*)salloc((size_t)NN * MAXN * 4);
    int*   gIdx = (int*)salloc((size_t)NN * MAXN * 4);
    float* X1  = (float*)salloc(NV * 4);
    float* X2  = (float*)salloc(NV * 4);   // contiguous with X1 (NV*4 is 256-mult)
    float* Wh1 = (float*)salloc(NV * 4);
    float* Wh2 = (float*)salloc(NV * 4);
    float* A1  = (float*)salloc(NV * 4);
    float* A2  = (float*)salloc(NV * 4);
    float* z   = (float*)salloc(NV * 4);
    float* za  = (float*)salloc(NV * 4);
    float* g   = (float*)salloc(NV * 4);
    float* ga  = (float*)salloc(NV * 4);
    float* De  = (float*)salloc(NV * 4);
    float* Dea = (float*)salloc(NV * 4);
    float* Dg  = (float*)salloc(NV * 4);
    float* Dga = (float*)salloc(NV * 4);
    float* s1  = (float*)salloc(NN * 4);
    float* s2  = (float*)salloc(NN * 4);
    float* d1  = (float*)salloc(NN * 4);
    float* d2  = (float*)salloc(NN * 4);
    // soff ~= 20.1 MB < 20.15 MB window: fits.

    float* w1f   = wA + 0;
    float* attWf = wA + 192000;
    float* asrcf = wA + 196096;
    float* adstf = wA + 196160;
    float* mW1f  = wA + 196224;
    float* mb1f  = wA + 212608;
    float* mW2f  = wA + 212864;
    float* mb2f  = wA + 245632;
    float* mW3f  = wA + 245760;
    float* mb3f  = wA + 253952;
    float* dW1f  = wA + 254016;
    float* db1f  = wA + 262208;
    float* dW2f  = wA + 262336;
    float* db2f  = wA + 270528;
    float* bWf   = wA + 270592;
    float* bbf   = wA + 274688;

    // BtH/BtL (split-bf16 W1^T, 385 KB each) park in De/Dea (dead until k_dmlp).
    u16* BtH = (u16*)De;
    u16* BtL = (u16*)Dea;

    k_detect<<<1, 1024, 0, stream>>>((const u16*)feat, flag);
    k_convw<<<dim3(750, 16), 256, 0, stream>>>(flag,
        w1, attW, a_src, a_dst, mW1, mb1, mW2, mb2, mW3, mb3,
        dW1, db1, dW2, db2, bW, bb, wA);
    k_convw2t<<<752, 256, 0, stream>>>(flag, w2, W2tH, W2tL);
    k_convw1t<<<752, 256, 0, stream>>>(flag, w1, BtH, BtL);
    k_build_csr<<<dim3(NN, 2), 256, 0, stream>>>(flag, adj, gn, aCnt, aIdx, gCnt, gIdx);
    hipMemsetAsync(X1, 0, 2 * NV * 4, stream);   // zero X1+X2 for f32 K-split atomics
    k_featgemm_mfma<<<dim3(NN / 32, 2), 512, 0, stream>>>(flag, feat, feat_a, BtH, X1, X2);
    k_featgemm_mfma_f32<<<dim3(NN / 64, 2, 4), 256, 0, stream>>>(flag, feat, feat_a, BtH, BtL, X1, X2);
    k_whsd<<<dim3(NN / 4, 2), 256, 0, stream>>>(X1, X2, attWf, asrcf, adstf, Wh1, Wh2, s1, s2, d1, d2);
    k_attn<<<dim3(NN, 2), 128, 0, stream>>>(aCnt, aIdx, s1, s2, d1, d2, Wh1, Wh2, A1, A2);
    k_mlp<<<dim3(NN / 4, 2), 256, 0, stream>>>(flag, A1, A2, mW1f, mb1f, mW2f, mb2f, mW3f, mb3f, z, za, d_out);
    k_readout<<<dim3(NN, 2), 64, 0, stream>>>(gCnt, gIdx, z, za, g, ga);
    k_dmlp<<<dim3(NN / 4, 4), 128, 0, stream>>>(z, za, g, ga, dW1f, db1f, dW2f, db2f, De, Dea, Dg, Dga);
    k_bilin_pre<<<dim3(64, 2), 256, 0, stream>>>(Dg, Dga, bWf, A1, A2);   // A1/A2 dead after k_mlp
    k_bilin_dot<<<dim3(NN / 4, 4), 256, 0, stream>>>(flag, De, Dea, A1, A2, bbf, d_out);
    k_spmm<<<NN, 64, 0, stream>>>(aCnt, aIdx, z, T);
    k_hgemm_mfma<<<dim3(NN / 32, 24), 256, 0, stream>>>(flag, T, W2tH, W2tL, d_out);
}

// Round 8
// 446.158 us; speedup vs baseline: 1.0782x; 1.0062x over previous
//
#include <hip/hip_runtime.h>

#define NN   4096
#define FIN  3000
#define MAXN 128

typedef unsigned short u16;
typedef __bf16 bf16x8 __attribute__((ext_vector_type(8)));
typedef float f32x16 __attribute__((ext_vector_type(16)));

__device__ __forceinline__ float bf2f(u16 u) { union { unsigned int i; float f; } v; v.i = ((unsigned int)u) << 16; return v.f; }
__device__ __forceinline__ u16 f2bf(float f) {
    union { float f; unsigned int i; } v; v.f = f;
    return (u16)((v.i + 0x7FFFu + ((v.i >> 16) & 1u)) >> 16);
}
__device__ __forceinline__ bf16x8 bzero8() {
    union { unsigned long long q[2]; bf16x8 v; } u; u.q[0] = 0ull; u.q[1] = 0ull; return u.v;
}
__device__ __forceinline__ f32x16 fzero16() {
    f32x16 v;
    #pragma unroll
    for (int i = 0; i < 16; i++) v[i] = 0.f;
    return v;
}
// async global->LDS, 16B per lane; dest = ldsbase + lane*16 (HW-fixed layout)
__device__ __forceinline__ void gload_lds16(const void* src, void* ldsbase) {
    __builtin_amdgcn_global_load_lds(
        (const __attribute__((address_space(1))) void*)src,
        (__attribute__((address_space(3))) void*)ldsbase, 16, 0, 0);
}

// ---- dtype detector: bf16 N(0,1) u16s have exponent ~127; f32-as-u16 halves are random.
__global__ __launch_bounds__(1024) void k_detect(const u16* __restrict__ feat, int* __restrict__ flag)
{
    __shared__ int tot;
    if (threadIdx.x == 0) tot = 0;
    __syncthreads();
    int ins = 0;
    for (int i = threadIdx.x; i < 16384; i += 1024) {
        u16 u = feat[i];
        int e = (u >> 7) & 0xFF;
        if (u != 0 && (e < 90 || e > 160)) ins++;
    }
    atomicAdd(&tot, ins);
    __syncthreads();
    if (threadIdx.x == 0) *flag = (tot > 1024) ? 1 : 0;   // 1 = inputs are f32
}

// ---- convert 16 weight tensors -> f32 arena (blockIdx.y = segment) ----
__global__ __launch_bounds__(256) void k_convw(const int* __restrict__ flag,
    const void* s0, const void* s1, const void* s2, const void* s3,
    const void* s4, const void* s5, const void* s6, const void* s7,
    const void* s8, const void* s9, const void* s10, const void* s11,
    const void* s12, const void* s13, const void* s14, const void* s15,
    float* __restrict__ dst)
{
    const void* srcs[16] = {s0,s1,s2,s3,s4,s5,s6,s7,s8,s9,s10,s11,s12,s13,s14,s15};
    const int offs[16] = {0,192000,196096,196160,196224,212608,212864,245632,245760,253952,254016,262208,262336,270528,270592,274688};
    const int ns[16]   = {192000,4096,64,64,16384,256,32768,128,8192,64,8192,128,8192,64,4096,1};
    int seg = blockIdx.y;
    int i = blockIdx.x * 256 + threadIdx.x;
    if (i >= ns[seg]) return;
    float v = (*flag) ? ((const float*)srcs[seg])[i] : bf2f(((const u16*)srcs[seg])[i]);
    dst[offs[seg] + i] = v;
}

// ---- build W2tH/W2tL = split-bf16 W2^T [3008][64] (n-major), zero-padded in n ----
__global__ __launch_bounds__(256) void k_convw2t(const int* __restrict__ flag,
    const void* __restrict__ src, u16* __restrict__ WH, u16* __restrict__ WL)
{
    int i = blockIdx.x * 256 + threadIdx.x;      // over 3008*64
    if (i >= 3008 * 64) return;
    int n = i >> 6, k = i & 63;
    float v = 0.f;
    if (n < FIN)
        v = (*flag) ? ((const float*)src)[(size_t)k * FIN + n]
                    : bf2f(((const u16*)src)[(size_t)k * FIN + n]);
    u16 h = f2bf(v);
    float r = v - bf2f(h);                       // exact in f32
    WH[i] = h;
    WL[i] = f2bf(r);
}

// ---- build BtH/BtL = split-bf16 W1^T [64][3008], zero-padded in k ----
__global__ __launch_bounds__(256) void k_convw1t(const int* __restrict__ flag,
    const void* __restrict__ w1src, u16* __restrict__ BtH, u16* __restrict__ BtL)
{
    int i = blockIdx.x * 256 + threadIdx.x;      // over 64*3008
    if (i >= 64 * 3008) return;
    int c = i / 3008, k = i - c * 3008;
    float v = 0.f;
    if (k < 3000)
        v = (*flag) ? ((const float*)w1src)[(size_t)k * 64 + c]
                    : bf2f(((const u16*)w1src)[(size_t)k * 64 + c]);
    u16 h = f2bf(v);
    float r = v - bf2f(h);                       // exact in f32
    BtH[(size_t)c * 3008 + k] = h;
    BtL[(size_t)c * 3008 + k] = f2bf(r);
}

// ---- ordered CSR build (prefix-scan, deterministic, sorted) for adj / graph_neigh ----
__global__ __launch_bounds__(256) void k_build_csr(const int* __restrict__ flag,
    const void* __restrict__ Av, const void* __restrict__ Gv,
    int* __restrict__ aCnt, int* __restrict__ aIdx,
    int* __restrict__ gCnt, int* __restrict__ gIdx)
{
    bool isf = (*flag != 0);
    const void* M = blockIdx.y ? Gv : Av;
    int* cnt = blockIdx.y ? gCnt : aCnt;
    int* idx = blockIdx.y ? gIdx : aIdx;
    int row = blockIdx.x, t = threadIdx.x;
    int c0 = t * 16;
    unsigned int mask = 0; int my = 0;
    if (isf) {
        const float4* r = (const float4*)((const float*)M + (size_t)row * NN + c0);
        union { float4 q[4]; float f[16]; } u;
        u.q[0] = r[0]; u.q[1] = r[1]; u.q[2] = r[2]; u.q[3] = r[3];
        #pragma unroll
        for (int j = 0; j < 16; j++) if (u.f[j] != 0.f) { mask |= 1u << j; my++; }
    } else {
        const uint4* r = (const uint4*)((const u16*)M + (size_t)row * NN + c0);
        union { uint4 q[2]; u16 h[16]; } u;
        u.q[0] = r[0]; u.q[1] = r[1];
        #pragma unroll
        for (int j = 0; j < 16; j++) if (u.h[j] != 0) { mask |= 1u << j; my++; }
    }
    __shared__ int sc[256];
    sc[t] = my;
    __syncthreads();
    for (int d = 1; d < 256; d <<= 1) {
        int v = (t >= d) ? sc[t - d] : 0;
        __syncthreads();
        sc[t] += v;
        __syncthreads();
    }
    int pos = sc[t] - my;
    for (int j = 0; j < 16; j++) {
        if (mask & (1u << j)) {
            if (pos < MAXN) idx[(size_t)row * MAXN + pos] = c0 + j;
            pos++;
        }
    }
    if (t == 0) { int total = sc[255]; cnt[row] = (total < MAXN) ? total : MAXN; }
}

// ---- bf16-input path: X = feat @ weight1 via 1-term v_mfma_f32_32x32x16_bf16 ----
__global__ __launch_bounds__(512) void k_featgemm_mfma(const int* __restrict__ flag,
    const void* __restrict__ F0v, const void* __restrict__ F1v,
    const u16* __restrict__ BtH, float* __restrict__ X0, float* __restrict__ X1)
{
    if (*flag) return;                     // f32 mode: handled by k_featgemm_mfma_f32
    const u16* F = (const u16*)(blockIdx.y ? F1v : F0v);
    float* X = blockIdx.y ? X1 : X0;
    int r0 = blockIdx.x * 32;
    int tid = threadIdx.x;
    int w  = tid >> 6;                     // wave id = K-eighth
    int l  = tid & 63;
    int lr = l & 31;                       // A row / B col / D col
    int kg = l >> 5;                       // k-group (0..1), 8 elems each
    const u16* arow = F   + (size_t)(r0 + lr) * FIN + kg * 8;
    const u16* b0p  = BtH + (size_t)lr * 3008 + kg * 8;
    const u16* b1p  = BtH + (size_t)(lr + 32) * 3008 + kg * 8;
    f32x16 acc0 = fzero16(), acc1 = fzero16();
    #pragma unroll 4
    for (int s = w; s < 188; s += 8) {
        int kk = s * 16;
        bf16x8 a;
        if (kk + kg * 8 < FIN) a = *(const bf16x8*)(arow + kk);
        else                   a = bzero8();
        bf16x8 b0 = *(const bf16x8*)(b0p + kk);   // Bt zero-padded to 3008
        bf16x8 b1 = *(const bf16x8*)(b1p + kk);
        acc0 = __builtin_amdgcn_mfma_f32_32x32x16_bf16(a, b0, acc0, 0, 0, 0);
        acc1 = __builtin_amdgcn_mfma_f32_32x32x16_bf16(a, b1, acc1, 0, 0, 0);
    }
    __shared__ float red[8][2048];         // 64 KB: per-wave 32x64 partials
    float* rp = red[w];
    #pragma unroll
    for (int reg = 0; reg < 16; reg++) {
        int row = (reg & 3) + 8 * (reg >> 2) + 4 * kg;
        rp[row * 64 + lr] = acc0[reg];
    }
    #pragma unroll
    for (int reg = 0; reg < 16; reg++) {
        int row = (reg & 3) + 8 * (reg >> 2) + 4 * kg;
        rp[row * 64 + 32 + lr] = acc1[reg];
    }
    __syncthreads();
    for (int i = tid; i < 2048; i += 512) {
        float s0 = 0.f;
        #pragma unroll
        for (int j = 0; j < 8; j++) s0 += red[j][i];
        X[(size_t)r0 * 64 + i] = s0;
    }
}

// ---- f32-input path: X = feat @ weight1 via split-bf16 3-term MFMA ----
// Round-8: fully LDS-fed compute (round-7 post-mortem: per-lane global B-loads
// in the compute section forced in-order vmcnt retirement of the async STAGE
// ops via the compiler's own B-load waits -> pipeline silently serialized).
//  * Stage A AND B(H,L) via global_load_lds: per step-buffer 32 KB
//    (A 16K + BH 8K + BL 8K); 2 buffers = 64 KB -> 2 blocks/CU.
//  * Compute section touches ONLY LDS (lgkmcnt domain) -> the counted
//    `s_waitcnt vmcnt(8)` at the loop top is the sole vmem wait: stage(s)
//    complete, stage(s+1)'s 8 ops in flight.
//  * B LDS layout [k-granule(8)][col(64)] x 16B: staging = lane->col, regular;
//    reads 16B-stride (~4-way bank alias, non-critical).
//  * Two barriers/step: ready-barrier after the wait; reuse-barrier after
//    compute (all waves done reading buf before next STAGE overwrites it).
__global__ __launch_bounds__(256) void k_featgemm_mfma_f32(const int* __restrict__ flag,
    const void* __restrict__ F0v, const void* __restrict__ F1v,
    const u16* __restrict__ BtH, const u16* __restrict__ BtL,
    float* __restrict__ X0, float* __restrict__ X1)
{
    if (!*flag) return;                    // bf16 mode: handled by k_featgemm_mfma
    const float* F = (const float*)(blockIdx.y ? F1v : F0v);
    float* X = blockIdx.y ? X1 : X0;
    int tid = threadIdx.x;
    int w  = tid >> 6;                     // wave id
    int l  = tid & 63;
    int lr = l & 31;
    int kg = l >> 5;                       // k-group (0..1), 8 elems each
    int wr = w >> 1, wc = w & 1;           // 2x2 wave grid
    int r0 = blockIdx.x * 64;
    int chunk = blockIdx.z;                // 0..3
    int sbeg = chunk * 12;
    int nsteps = (chunk == 3) ? 11 : 12;

    __shared__ char lds[2][32768];         // per buf: A[16K] + BH[8K] + BL[8K]

    const float* Fb = F + (size_t)r0 * FIN;
    int arow = 32 * wr + lr;               // LDS A row this lane reads
    int acol = 32 * wc + lr;               // B col = output col
    int slin = (w * 16) * 256 + l * 16;    // linear A-LDS byte of lane's 16B
    f32x16 acc = fzero16();

    auto STAGE = [&](int s, int buf) {
        int kbase = (sbeg + s) * 64;
        char* base = lds[buf];
        #pragma unroll
        for (int j = 0; j < 4; j++) {      // A: swizzled source, linear dest
            int lin = slin + j * 1024;
            int row = lin >> 8;
            int off = (lin & 255) ^ ((row & 15) << 4);
            gload_lds16((const void*)(Fb + (size_t)row * FIN + kbase + (off >> 2)),
                        base + (w * 16 + j * 4) * 256);
        }
        #pragma unroll
        for (int j = 0; j < 2; j++) {      // BH: granule (w*2+j)*64 + l
            int kgrp = w * 2 + j;
            gload_lds16((const void*)(BtH + (size_t)l * 3008 + kbase + kgrp * 8),
                        base + 16384 + kgrp * 1024);
        }
        #pragma unroll
        for (int j = 0; j < 2; j++) {      // BL
            int kgrp = w * 2 + j;
            gload_lds16((const void*)(BtL + (size_t)l * 3008 + kbase + kgrp * 8),
                        base + 24576 + kgrp * 1024);
        }
    };

    STAGE(0, 0);

    for (int s = 0; s < nsteps; ++s) {
        if (s + 1 < nsteps) {
            STAGE(s + 1, (s + 1) & 1);     // buf consumed at s-1, barrier'd
            asm volatile("s_waitcnt vmcnt(8)" ::: "memory");  // stage(s) done
        } else {
            asm volatile("s_waitcnt vmcnt(0)" ::: "memory");
        }
        __builtin_amdgcn_s_barrier();      // buf[s] globally ready
        const char* lb = lds[s & 1];
        const char* Bh = lb + 16384;
        const char* Bl = lb + 24576;
        #pragma unroll
        for (int s16 = 0; s16 < 4; s16++) {
            int offu = s16 * 64 + kg * 32;
            int o0 = offu        ^ ((arow & 15) << 4);
            int o1 = (offu + 16) ^ ((arow & 15) << 4);
            float4 a0 = *(const float4*)(lb + arow * 256 + o0);
            float4 a1 = *(const float4*)(lb + arow * 256 + o1);
            float av[8] = {a0.x, a0.y, a0.z, a0.w, a1.x, a1.y, a1.z, a1.w};
            bf16x8 ah, al;
            #pragma unroll
            for (int jj = 0; jj < 8; jj++) {
                __bf16 hv = (__bf16)av[jj];
                ah[jj] = hv;
                al[jj] = (__bf16)(av[jj] - (float)hv);   // exact residual
            }
            int kgrp = s16 * 2 + kg;
            bf16x8 H = *(const bf16x8*)(Bh + (kgrp * 64 + acol) * 16);
            bf16x8 L = *(const bf16x8*)(Bl + (kgrp * 64 + acol) * 16);
            acc = __builtin_amdgcn_mfma_f32_32x32x16_bf16(ah, H, acc, 0, 0, 0);
            acc = __builtin_amdgcn_mfma_f32_32x32x16_bf16(al, H, acc, 0, 0, 0);
            acc = __builtin_amdgcn_mfma_f32_32x32x16_bf16(ah, L, acc, 0, 0, 0);
        }
        __builtin_amdgcn_s_barrier();      // all waves done reading buf[s]
    }

    // 4-way K-chunk reduce (X pre-zeroed; L2-resident atomics)
    #pragma unroll
    for (int reg = 0; reg < 16; reg++) {
        int row = (reg & 3) + 8 * (reg >> 2) + 4 * kg;
        atomicAdd(&X[(size_t)(r0 + 32 * wr + row) * 64 + acol], acc[reg]);
    }
}

// ---- Wh = X @ att_W; s = Wh@a_src; d = Wh@a_dst; 4 rows/block, attW in LDS ----
__global__ __launch_bounds__(256) void k_whsd(
    const float* __restrict__ X1, const float* __restrict__ X2,
    const float* __restrict__ AW, const float* __restrict__ asrc, const float* __restrict__ adst,
    float* __restrict__ Wh1, float* __restrict__ Wh2,
    float* __restrict__ s1, float* __restrict__ s2,
    float* __restrict__ d1, float* __restrict__ d2)
{
    const float* X = blockIdx.y ? X2 : X1;
    float* Wh = blockIdx.y ? Wh2 : Wh1;
    float* sv = blockIdx.y ? s2 : s1;
    float* dv = blockIdx.y ? d2 : d1;
    __shared__ float aw[64][65];           // padded
    __shared__ float x[4][65];
    int tid = threadIdx.x;
    for (int i = tid; i < 4096; i += 256) aw[i >> 6][i & 63] = AW[i];
    int g = tid >> 6, c = tid & 63;
    int row = blockIdx.x * 4 + g;
    x[g][c] = X[(size_t)row * 64 + c];
    __syncthreads();
    float acc = 0.f;
    #pragma unroll 16
    for (int k = 0; k < 64; k++) acc += x[g][k] * aw[k][c];
    Wh[(size_t)row * 64 + c] = acc;
    float vs = acc * asrc[c];
    float vd = acc * adst[c];
    #pragma unroll
    for (int off = 32; off > 0; off >>= 1) { vs += __shfl_down(vs, off); vd += __shfl_down(vd, off); }
    if (c == 0) { sv[row] = vs; dv[row] = vd; }
}

// ---- masked softmax (rank-1 scores) + P @ Wh over CSR neighbors ----
__global__ __launch_bounds__(128) void k_attn(
    const int* __restrict__ cnt, const int* __restrict__ idx,
    const float* __restrict__ s1, const float* __restrict__ s2,
    const float* __restrict__ d1, const float* __restrict__ d2,
    const float* __restrict__ Wh1, const float* __restrict__ Wh2,
    float* __restrict__ A1, float* __restrict__ A2)
{
    const float* sp = blockIdx.y ? s2 : s1;
    const float* dp = blockIdx.y ? d2 : d1;
    const float* Wh = blockIdx.y ? Wh2 : Wh1;
    float* A = blockIdx.y ? A2 : A1;
    int row = blockIdx.x, tid = threadIdx.x;
    int n = cnt[row];
    __shared__ int js[MAXN];
    __shared__ float ps[MAXN];
    __shared__ float red2[2];
    __shared__ float ared[2][64];
    for (int k = tid; k < n; k += 128) js[k] = idx[(size_t)row * MAXN + k];
    __syncthreads();
    float si = sp[row];
    float m = -3.0e38f;
    for (int k = tid; k < n; k += 128) {
        float e = si + dp[js[k]];
        e = e > 0.f ? e : 0.2f * e;   // LeakyReLU(0.2)
        ps[k] = e;
        m = fmaxf(m, e);
    }
    #pragma unroll
    for (int off = 32; off > 0; off >>= 1) m = fmaxf(m, __shfl_down(m, off));
    if ((tid & 63) == 0) red2[tid >> 6] = m;
    __syncthreads();
    m = fmaxf(red2[0], red2[1]);
    __syncthreads();
    float zz = 0.f;
    for (int k = tid; k < n; k += 128) {
        float p = __expf(ps[k] - m);
        ps[k] = p;
        zz += p;
    }
    #pragma unroll
    for (int off = 32; off > 0; off >>= 1) zz += __shfl_down(zz, off);
    if ((tid & 63) == 0) red2[tid >> 6] = zz;
    __syncthreads();
    float Z = red2[0] + red2[1];
    Z = fmaxf(Z, 1e-20f);           // guard 0/0
    int f = tid & 63, half = tid >> 6;
    float acc = 0.f;
    for (int k = half; k < n; k += 2) acc += ps[k] * Wh[(size_t)js[k] * 64 + f];
    ared[half][f] = acc;
    __syncthreads();
    if (tid < 64) A[(size_t)row * 64 + f] = (ared[0][f] + ared[1][f]) / Z;
}

// ---- 3-layer MLP 64->256->128->64; 4 rows/block; writes z (f32) and hiden_emb (dual-dtype, y==0) ----
__global__ __launch_bounds__(256) void k_mlp(const int* __restrict__ flag,
    const float* __restrict__ A1, const float* __restrict__ A2,
    const float* __restrict__ W1, const float* __restrict__ b1,
    const float* __restrict__ W2, const float* __restrict__ b2,
    const float* __restrict__ W3, const float* __restrict__ b3,
    float* __restrict__ Z1, float* __restrict__ Z2, void* __restrict__ hidenv)
{
    const float* A = blockIdx.y ? A2 : A1;
    float* Z = blockIdx.y ? Z2 : Z1;
    int row0 = blockIdx.x * 4, tid = threadIdx.x;
    __shared__ float x[4][64], h1[4][256], h2[4][128];
    {
        int r = tid >> 6, c = tid & 63;
        x[r][c] = A[(size_t)(row0 + r) * 64 + c];
    }
    __syncthreads();
    {
        float a0 = b1[tid], a1v = a0, a2v = a0, a3v = a0;
        #pragma unroll 8
        for (int k = 0; k < 64; k++) {
            float w = W1[k * 256 + tid];
            a0 += x[0][k] * w; a1v += x[1][k] * w; a2v += x[2][k] * w; a3v += x[3][k] * w;
        }
        h1[0][tid] = fmaxf(a0, 0.f);  h1[1][tid] = fmaxf(a1v, 0.f);
        h1[2][tid] = fmaxf(a2v, 0.f); h1[3][tid] = fmaxf(a3v, 0.f);
    }
    __syncthreads();
    if (tid < 128) {
        float a0 = b2[tid], a1v = a0, a2v = a0, a3v = a0;
        #pragma unroll 8
        for (int k = 0; k < 256; k++) {
            float w = W2[k * 128 + tid];
            a0 += h1[0][k] * w; a1v += h1[1][k] * w; a2v += h1[2][k] * w; a3v += h1[3][k] * w;
        }
        h2[0][tid] = fmaxf(a0, 0.f);  h2[1][tid] = fmaxf(a1v, 0.f);
        h2[2][tid] = fmaxf(a2v, 0.f); h2[3][tid] = fmaxf(a3v, 0.f);
    }
    __syncthreads();
    if (tid < 64) {
        float a[4];
        a[0] = a[1] = a[2] = a[3] = b3[tid];
        #pragma unroll 8
        for (int k = 0; k < 128; k++) {
            float w = W3[k * 64 + tid];
            a[0] += h2[0][k] * w; a[1] += h2[1][k] * w; a[2] += h2[2][k] * w; a[3] += h2[3][k] * w;
        }
        bool isf = (*flag != 0);
        #pragma unroll
        for (int r = 0; r < 4; r++) {
            size_t ei = (size_t)(row0 + r) * 64 + tid;
            Z[ei] = a[r];
            if (blockIdx.y == 0) {
                if (isf) ((float*)hidenv)[ei] = a[r];
                else     ((u16*)hidenv)[ei] = f2bf(a[r]);
            }
        }
    }
}

// ---- T = adj @ z over CSR ----
__global__ __launch_bounds__(64) void k_spmm(
    const int* __restrict__ cnt, const int* __restrict__ idx,
    const float* __restrict__ Z, float* __restrict__ T)
{
    int row = blockIdx.x, f = threadIdx.x;
    int n = cnt[row];
    const int* ir = idx + (size_t)row * MAXN;
    float acc = 0.f;
    for (int k = 0; k < n; k++) acc += Z[(size_t)ir[k] * 64 + f];
    T[(size_t)row * 64 + f] = acc;
}

// ---- H = T @ weight2 via split-bf16 3-term MFMA -> out (dual-dtype store) ----
__global__ __launch_bounds__(256) void k_hgemm_mfma(const int* __restrict__ flag,
    const float* __restrict__ T, const u16* __restrict__ WH, const u16* __restrict__ WL,
    void* __restrict__ outv)
{
    bool isf = (*flag != 0);
    int tid = threadIdx.x;
    int w = tid >> 6, l = tid & 63, lr = l & 31, kg = l >> 5;
    int ct = blockIdx.y * 4 + w;
    if (ct >= 94) return;                  // wave-uniform; no barriers in kernel
    int r0 = blockIdx.x * 32, c0 = ct * 32;
    const float* tp = T + (size_t)(r0 + lr) * 64 + kg * 8;
    bf16x8 ah[4], al[4];
    #pragma unroll
    for (int s = 0; s < 4; s++) {
        float4 p0 = *(const float4*)(tp + s * 16);
        float4 p1 = *(const float4*)(tp + s * 16 + 4);
        float av[8] = {p0.x, p0.y, p0.z, p0.w, p1.x, p1.y, p1.z, p1.w};
        #pragma unroll
        for (int j = 0; j < 8; j++) {
            __bf16 hv = (__bf16)av[j];
            ah[s][j] = hv;
            al[s][j] = (__bf16)(av[j] - (float)hv);   // exact residual
        }
    }
    const u16* bh = WH + (size_t)(c0 + lr) * 64 + kg * 8;
    const u16* bl = WL + (size_t)(c0 + lr) * 64 + kg * 8;
    f32x16 acc = fzero16();
    #pragma unroll
    for (int s = 0; s < 4; s++) {
        bf16x8 vh = *(const bf16x8*)(bh + s * 16);
        bf16x8 vl = *(const bf16x8*)(bl + s * 16);
        acc = __builtin_amdgcn_mfma_f32_32x32x16_bf16(ah[s], vh, acc, 0, 0, 0);
        acc = __builtin_amdgcn_mfma_f32_32x32x16_bf16(al[s], vh, acc, 0, 0, 0);
        acc = __builtin_amdgcn_mfma_f32_32x32x16_bf16(ah[s], vl, acc, 0, 0, 0);
    }
    int col = c0 + lr;
    bool cok = col < FIN;
    #pragma unroll
    for (int reg = 0; reg < 16; reg++) {
        int row = (reg & 3) + 8 * (reg >> 2) + 4 * kg;
        size_t ei = 262144 + (size_t)(r0 + row) * FIN + col;
        if (cok) {
            if (isf) ((float*)outv)[ei] = acc[reg];
            else     ((u16*)outv)[ei] = f2bf(acc[reg]);
        }
    }
}

// ---- readout: mean over graph_neigh nbrs of relu(z), L2 normalize, sigmoid ----
__global__ __launch_bounds__(64) void k_readout(
    const int* __restrict__ cnt, const int* __restrict__ idx,
    const float* __restrict__ Z1, const float* __restrict__ Z2,
    float* __restrict__ G1, float* __restrict__ G2)
{
    const float* Z = blockIdx.y ? Z2 : Z1;
    float* G = blockIdx.y ? G2 : G1;
    int row = blockIdx.x, f = threadIdx.x;
    int n = cnt[row];
    const int* ir = idx + (size_t)row * MAXN;
    float acc = 0.f;
    for (int k = 0; k < n; k++) acc += fmaxf(Z[(size_t)ir[k] * 64 + f], 0.f);
    acc /= (float)(n > 0 ? n : 1);
    float sq = acc * acc;
    #pragma unroll
    for (int off = 32; off > 0; off >>= 1) sq += __shfl_down(sq, off);
    sq = __shfl(sq, 0);
    float nrm = fmaxf(sqrtf(sq), 1e-12f);
    float v = acc / nrm;
    G[(size_t)row * 64 + f] = 1.f / (1.f + __expf(-v));
}

// ---- discriminator MLP 64->128->64; 4 rows/block; on {relu(z), relu(z_a), g, g_a} ----
__global__ __launch_bounds__(128) void k_dmlp(
    const float* __restrict__ z, const float* __restrict__ za,
    const float* __restrict__ g, const float* __restrict__ ga,
    const float* __restrict__ W1, const float* __restrict__ b1,
    const float* __restrict__ W2, const float* __restrict__ b2,
    float* __restrict__ De, float* __restrict__ Dea,
    float* __restrict__ Dg, float* __restrict__ Dga)
{
    int w = blockIdx.y;
    const float* X = (w == 0) ? z : (w == 1) ? za : (w == 2) ? g : ga;
    float* O = (w == 0) ? De : (w == 1) ? Dea : (w == 2) ? Dg : Dga;
    int doRelu = (w < 2);
    int row0 = blockIdx.x * 4, tid = threadIdx.x;
    __shared__ float x[4][64], h1[4][128];
    for (int i = tid; i < 256; i += 128) {
        int r = i >> 6, c = i & 63;
        float v = X[(size_t)(row0 + r) * 64 + c];
        x[r][c] = doRelu ? fmaxf(v, 0.f) : v;
    }
    __syncthreads();
    {
        float a0 = b1[tid], a1v = a0, a2v = a0, a3v = a0;
        #pragma unroll 8
        for (int k = 0; k < 64; k++) {
            float w_ = W1[k * 128 + tid];
            a0 += x[0][k] * w_; a1v += x[1][k] * w_; a2v += x[2][k] * w_; a3v += x[3][k] * w_;
        }
        h1[0][tid] = fmaxf(a0, 0.f);  h1[1][tid] = fmaxf(a1v, 0.f);
        h1[2][tid] = fmaxf(a2v, 0.f); h1[3][tid] = fmaxf(a3v, 0.f);
    }
    __syncthreads();
    if (tid < 64) {
        float a[4];
        a[0] = a[1] = a[2] = a[3] = b2[tid];
        #pragma unroll 8
        for (int k = 0; k < 128; k++) {
            float w_ = W2[k * 64 + tid];
            a[0] += h1[0][k] * w_; a[1] += h1[1][k] * w_; a[2] += h1[2][k] * w_; a[3] += h1[3][k] * w_;
        }
        #pragma unroll
        for (int r = 0; r < 4; r++) O[(size_t)(row0 + r) * 64 + tid] = a[r];
    }
}

// ---- bilinear stage 1: V = Y @ BW^T for Y in {Dg, Dga}; BW cached in LDS ----
__global__ __launch_bounds__(256) void k_bilin_pre(
    const float* __restrict__ Dg, const float* __restrict__ Dga,
    const float* __restrict__ BW, float* __restrict__ V1, float* __restrict__ V2)
{
    const float* Y = blockIdx.y ? Dga : Dg;
    float* V = blockIdx.y ? V2 : V1;
    __shared__ float bw[64][65];           // padded
    __shared__ float y[4][65];
    int tid = threadIdx.x;
    for (int i = tid; i < 4096; i += 256) bw[i >> 6][i & 63] = BW[i];
    int g = tid >> 6, k = tid & 63;
    int rbase = blockIdx.x * 64;
    for (int it = 0; it < 16; it++) {
        __syncthreads();
        int r = rbase + it * 4 + g;
        y[g][k] = Y[(size_t)r * 64 + k];
        __syncthreads();
        float acc = 0.f;
        #pragma unroll 16
        for (int j = 0; j < 64; j++) acc += y[g][j] * bw[k][j];
        V[(size_t)r * 64 + k] = acc;       // V[r][k] = (BW @ y_r)[k]
    }
}

// ---- bilinear stage 2: out = dot(x_r, V_r) + b ; 4 rows/block, dual-dtype ----
__global__ __launch_bounds__(256) void k_bilin_dot(const int* __restrict__ flag,
    const float* __restrict__ De, const float* __restrict__ Dea,
    const float* __restrict__ V1, const float* __restrict__ V2,
    const float* __restrict__ bb, void* __restrict__ outv)
{
    int w = blockIdx.y;
    const float* X = (w == 0 || w == 3) ? De : Dea;
    const float* V = (w <= 1) ? V1 : V2;
    size_t bse = (w <= 1) ? (size_t)12550144 : (size_t)12558336;
    int col = (w == 0 || w == 2) ? 0 : 1;
    int g = threadIdx.x >> 6, k = threadIdx.x & 63;
    int row = blockIdx.x * 4 + g;
    float v = X[(size_t)row * 64 + k] * V[(size_t)row * 64 + k];
    #pragma unroll
    for (int off = 32; off > 0; off >>= 1) v += __shfl_down(v, off);
    if (k == 0) {
        float r = v + bb[0];
        size_t ei = bse + (size_t)row * 2 + col;
        if (*flag) ((float*)outv)[ei] = r;
        else       ((u16*)outv)[ei] = f2bf(r);
    }
}

extern "C" void kernel_launch(void* const* d_in, const int* in_sizes, int n_in,
                              void* d_out, int out_size, void* d_ws, size_t ws_size,
                              hipStream_t stream) {
    const void* feat   = d_in[0];
    const void* feat_a = d_in[1];
    const void* adj    = d_in[2];
    const void* gn     = d_in[3];
    const void* w1     = d_in[4];
    const void* w2     = d_in[5];
    const void* attW   = d_in[6];
    const void* a_src  = d_in[7];
    const void* a_dst  = d_in[8];
    const void* mW1    = d_in[9];
    const void* mb1    = d_in[10];
    const void* mW2    = d_in[11];
    const void* mb2    = d_in[12];
    const void* mW3    = d_in[13];
    const void* mb3    = d_in[14];
    const void* dW1    = d_in[15];
    const void* db1    = d_in[16];
    const void* dW2    = d_in[17];
    const void* db2    = d_in[18];
    const void* bW     = d_in[19];
    const void* bb     = d_in[20];
    (void)in_sizes; (void)n_in; (void)out_size;

    // ---- d_ws: flag + T + W2tH/W2tL (~1.82 MB total) ----
    char* wsb = (char*)d_ws;
    int*   flag = (int*)wsb;                        // 4 B (pad 256)
    float* T    = (float*)(wsb + 256);              // 1,048,576 B
    u16*   W2tH = (u16*)(wsb + 256 + 1048576);      // 385,024 B
    u16*   W2tL = W2tH + 3008 * 64;                 // 385,024 B
    (void)ws_size;

    // ---- scratch arena at dtype-independent byte window of d_out ----
    char* sc = (char*)d_out + 1048576;
    size_t soff = 0;
    auto salloc = [&](size_t nbytes) -> void* {
        void* p = (void*)(sc + soff);
        soff += (nbytes + 255) & ~(size_t)255;
        return p;
    };
    const size_t NV = (size_t)NN * 64;
    float* wA   = (float*)salloc((size_t)274689 * 4);  // 16-segment f32 weight arena
    int*   aCnt = (int*)salloc(NN * 4);
    int*   gCnt = (int*)salloc(NN * 4);
    int*   aIdx = (int*)salloc((size_t)NN * MAXN * 4);
    int*   gIdx = (int*)salloc((size_t)NN * MAXN * 4);
    float* X1  = (float*)salloc(NV * 4);
    float* X2  = (float*)salloc(NV * 4);   // contiguous with X1 (NV*4 is 256-mult)
    float* Wh1 = (float*)salloc(NV * 4);
    float* Wh2 = (float*)salloc(NV * 4);
    float* A1  = (float*)salloc(NV * 4);
    float* A2  = (float*)salloc(NV * 4);
    float* z   = (float*)salloc(NV * 4);
    float* za  = (float*)salloc(NV * 4);
    float* g   = (float*)salloc(NV * 4);
    float* ga  = (float*)salloc(NV * 4);
    float* De  = (float*)salloc(NV * 4);
    float* Dea = (float*)salloc(NV * 4);
    float* Dg  = (float*)salloc(NV * 4);
    float* Dga = (float*)salloc(NV * 4);
    float* s1  = (float*)salloc(NN * 4);
    float* s2  = (float*)salloc(NN * 4);
    float* d1  = (float*)salloc(NN * 4);
    float* d2  = (float*)salloc(NN * 4);
    // soff ~= 20.1 MB < 20.15 MB window: fits.

    float* w1f   = wA + 0;
    float* attWf = wA + 192000;
    float* asrcf = wA + 196096;
    float* adstf = wA + 196160;
    float* mW1f  = wA + 196224;
    float* mb1f  = wA + 212608;
    float* mW2f  = wA + 212864;
    float* mb2f  = wA + 245632;
    float* mW3f  = wA + 245760;
    float* mb3f  = wA + 253952;
    float* dW1f  = wA + 254016;
    float* db1f  = wA + 262208;
    float* dW2f  = wA + 262336;
    float* db2f  = wA + 270528;
    float* bWf   = wA + 270592;
    float* bbf   = wA + 274688;

    // BtH/BtL (split-bf16 W1^T, 385 KB each) park in De/Dea (dead until k_dmlp).
    u16* BtH = (u16*)De;
    u16* BtL = (u16*)Dea;

    k_detect<<<1, 1024, 0, stream>>>((const u16*)feat, flag);
    k_convw<<<dim3(750, 16), 256, 0, stream>>>(flag,
        w1, attW, a_src, a_dst, mW1, mb1, mW2, mb2, mW3, mb3,
        dW1, db1, dW2, db2, bW, bb, wA);
    k_convw2t<<<752, 256, 0, stream>>>(flag, w2, W2tH, W2tL);
    k_convw1t<<<752, 256, 0, stream>>>(flag, w1, BtH, BtL);
    k_build_csr<<<dim3(NN, 2), 256, 0, stream>>>(flag, adj, gn, aCnt, aIdx, gCnt, gIdx);
    hipMemsetAsync(X1, 0, 2 * NV * 4, stream);   // zero X1+X2 for f32 K-split atomics
    k_featgemm_mfma<<<dim3(NN / 32, 2), 512, 0, stream>>>(flag, feat, feat_a, BtH, X1, X2);
    k_featgemm_mfma_f32<<<dim3(NN / 64, 2, 4), 256, 0, stream>>>(flag, feat, feat_a, BtH, BtL, X1, X2);
    k_whsd<<<dim3(NN / 4, 2), 256, 0, stream>>>(X1, X2, attWf, asrcf, adstf, Wh1, Wh2, s1, s2, d1, d2);
    k_attn<<<dim3(NN, 2), 128, 0, stream>>>(aCnt, aIdx, s1, s2, d1, d2, Wh1, Wh2, A1, A2);
    k_mlp<<<dim3(NN / 4, 2), 256, 0, stream>>>(flag, A1, A2, mW1f, mb1f, mW2f, mb2f, mW3f, mb3f, z, za, d_out);
    k_readout<<<dim3(NN, 2), 64, 0, stream>>>(gCnt, gIdx, z, za, g, ga);
    k_dmlp<<<dim3(NN / 4, 4), 128, 0, stream>>>(z, za, g, ga, dW1f, db1f, dW2f, db2f, De, Dea, Dg, Dga);
    k_bilin_pre<<<dim3(64, 2), 256, 0, stream>>>(Dg, Dga, bWf, A1, A2);   // A1/A2 dead after k_mlp
    k_bilin_dot<<<dim3(NN / 4, 4), 256, 0, stream>>>(flag, De, Dea, A1, A2, bbf, d_out);
    k_spmm<<<NN, 64, 0, stream>>>(aCnt, aIdx, z, T);
    k_hgemm_mfma<<<dim3(NN / 32, 24), 256, 0, stream>>>(flag, T, W2tH, W2tL, d_out);
}

// Round 9
// 442.351 us; speedup vs baseline: 1.0875x; 1.0086x over previous
//
#include <hip/hip_runtime.h>

#define NN   4096
#define FIN  3000
#define MAXN 128

typedef unsigned short u16;
typedef __bf16 bf16x8 __attribute__((ext_vector_type(8)));
typedef float f32x16 __attribute__((ext_vector_type(16)));

__device__ __forceinline__ float bf2f(u16 u) { union { unsigned int i; float f; } v; v.i = ((unsigned int)u) << 16; return v.f; }
__device__ __forceinline__ u16 f2bf(float f) {
    union { float f; unsigned int i; } v; v.f = f;
    return (u16)((v.i + 0x7FFFu + ((v.i >> 16) & 1u)) >> 16);
}
__device__ __forceinline__ bf16x8 bzero8() {
    union { unsigned long long q[2]; bf16x8 v; } u; u.q[0] = 0ull; u.q[1] = 0ull; return u.v;
}
__device__ __forceinline__ f32x16 fzero16() {
    f32x16 v;
    #pragma unroll
    for (int i = 0; i < 16; i++) v[i] = 0.f;
    return v;
}
// async global->LDS, 16B per lane; dest = ldsbase + lane*16 (HW-fixed layout)
__device__ __forceinline__ void gload_lds16(const void* src, void* ldsbase) {
    __builtin_amdgcn_global_load_lds(
        (const __attribute__((address_space(1))) void*)src,
        (__attribute__((address_space(3))) void*)ldsbase, 16, 0, 0);
}

// ---- dtype detector: bf16 N(0,1) u16s have exponent ~127; f32-as-u16 halves are random.
__global__ __launch_bounds__(1024) void k_detect(const u16* __restrict__ feat, int* __restrict__ flag)
{
    __shared__ int tot;
    if (threadIdx.x == 0) tot = 0;
    __syncthreads();
    int ins = 0;
    for (int i = threadIdx.x; i < 16384; i += 1024) {
        u16 u = feat[i];
        int e = (u >> 7) & 0xFF;
        if (u != 0 && (e < 90 || e > 160)) ins++;
    }
    atomicAdd(&tot, ins);
    __syncthreads();
    if (threadIdx.x == 0) *flag = (tot > 1024) ? 1 : 0;   // 1 = inputs are f32
}

// ---- convert 16 weight tensors -> f32 arena (blockIdx.y = segment) ----
__global__ __launch_bounds__(256) void k_convw(const int* __restrict__ flag,
    const void* s0, const void* s1, const void* s2, const void* s3,
    const void* s4, const void* s5, const void* s6, const void* s7,
    const void* s8, const void* s9, const void* s10, const void* s11,
    const void* s12, const void* s13, const void* s14, const void* s15,
    float* __restrict__ dst)
{
    const void* srcs[16] = {s0,s1,s2,s3,s4,s5,s6,s7,s8,s9,s10,s11,s12,s13,s14,s15};
    const int offs[16] = {0,192000,196096,196160,196224,212608,212864,245632,245760,253952,254016,262208,262336,270528,270592,274688};
    const int ns[16]   = {192000,4096,64,64,16384,256,32768,128,8192,64,8192,128,8192,64,4096,1};
    int seg = blockIdx.y;
    int i = blockIdx.x * 256 + threadIdx.x;
    if (i >= ns[seg]) return;
    float v = (*flag) ? ((const float*)srcs[seg])[i] : bf2f(((const u16*)srcs[seg])[i]);
    dst[offs[seg] + i] = v;
}

// ---- fused weight transposes (blockIdx.y selects slice) ----
// y=0: W2tH/W2tL = split-bf16 W2^T [3008][64], zero-padded in n.
// y=1: BtGH/BtGL = split-bf16 W1^T GRANULE-MAJOR [g=k/8][col][8] -- the exact
//      LDS image the featgemm staging wants, so staging is lane-contiguous
//      (round-8 post-mortem: old [64][3008] layout made every B-stage
//      instruction a 64-cache-line scatter).
// y=2: BtH_old = bf16 W1^T [64][3008] (H only) for the bf16-input fallback.
__global__ __launch_bounds__(256) void k_convwt(const int* __restrict__ flag,
    const void* __restrict__ w1src, const void* __restrict__ w2src,
    u16* __restrict__ BtGH, u16* __restrict__ BtGL,
    u16* __restrict__ W2tH, u16* __restrict__ W2tL,
    u16* __restrict__ BtHold)
{
    bool isf = (*flag != 0);
    int i = blockIdx.x * 256 + threadIdx.x;
    if (blockIdx.y == 0) {
        if (i >= 3008 * 64) return;
        int n = i >> 6, k = i & 63;
        float v = 0.f;
        if (n < FIN)
            v = isf ? ((const float*)w2src)[(size_t)k * FIN + n]
                    : bf2f(((const u16*)w2src)[(size_t)k * FIN + n]);
        u16 h = f2bf(v);
        W2tH[i] = h;
        W2tL[i] = f2bf(v - bf2f(h));
    } else if (blockIdx.y == 1) {
        if (i >= 376 * 512) return;        // g*512 + c*8 + e
        int g = i >> 9, rem = i & 511, c = rem >> 3, e = rem & 7;
        int k = g * 8 + e;
        float v = 0.f;
        if (k < FIN)
            v = isf ? ((const float*)w1src)[(size_t)k * 64 + c]
                    : bf2f(((const u16*)w1src)[(size_t)k * 64 + c]);
        u16 h = f2bf(v);
        BtGH[i] = h;
        BtGL[i] = f2bf(v - bf2f(h));
    } else {
        if (i >= 64 * 3008) return;
        int c = i / 3008, k = i - c * 3008;
        float v = 0.f;
        if (k < FIN)
            v = isf ? ((const float*)w1src)[(size_t)k * 64 + c]
                    : bf2f(((const u16*)w1src)[(size_t)k * 64 + c]);
        BtHold[i] = f2bf(v);
    }
}

// ---- ordered CSR build (prefix-scan, deterministic, sorted) for adj / graph_neigh ----
__global__ __launch_bounds__(256) void k_build_csr(const int* __restrict__ flag,
    const void* __restrict__ Av, const void* __restrict__ Gv,
    int* __restrict__ aCnt, int* __restrict__ aIdx,
    int* __restrict__ gCnt, int* __restrict__ gIdx)
{
    bool isf = (*flag != 0);
    const void* M = blockIdx.y ? Gv : Av;
    int* cnt = blockIdx.y ? gCnt : aCnt;
    int* idx = blockIdx.y ? gIdx : aIdx;
    int row = blockIdx.x, t = threadIdx.x;
    int c0 = t * 16;
    unsigned int mask = 0; int my = 0;
    if (isf) {
        const float4* r = (const float4*)((const float*)M + (size_t)row * NN + c0);
        union { float4 q[4]; float f[16]; } u;
        u.q[0] = r[0]; u.q[1] = r[1]; u.q[2] = r[2]; u.q[3] = r[3];
        #pragma unroll
        for (int j = 0; j < 16; j++) if (u.f[j] != 0.f) { mask |= 1u << j; my++; }
    } else {
        const uint4* r = (const uint4*)((const u16*)M + (size_t)row * NN + c0);
        union { uint4 q[2]; u16 h[16]; } u;
        u.q[0] = r[0]; u.q[1] = r[1];
        #pragma unroll
        for (int j = 0; j < 16; j++) if (u.h[j] != 0) { mask |= 1u << j; my++; }
    }
    __shared__ int sc[256];
    sc[t] = my;
    __syncthreads();
    for (int d = 1; d < 256; d <<= 1) {
        int v = (t >= d) ? sc[t - d] : 0;
        __syncthreads();
        sc[t] += v;
        __syncthreads();
    }
    int pos = sc[t] - my;
    for (int j = 0; j < 16; j++) {
        if (mask & (1u << j)) {
            if (pos < MAXN) idx[(size_t)row * MAXN + pos] = c0 + j;
            pos++;
        }
    }
    if (t == 0) { int total = sc[255]; cnt[row] = (total < MAXN) ? total : MAXN; }
}

// ---- bf16-input path: X = feat @ weight1 via 1-term v_mfma_f32_32x32x16_bf16 ----
__global__ __launch_bounds__(512) void k_featgemm_mfma(const int* __restrict__ flag,
    const void* __restrict__ F0v, const void* __restrict__ F1v,
    const u16* __restrict__ BtH, float* __restrict__ X0, float* __restrict__ X1)
{
    if (*flag) return;                     // f32 mode: handled by k_featgemm_mfma_f32
    const u16* F = (const u16*)(blockIdx.y ? F1v : F0v);
    float* X = blockIdx.y ? X1 : X0;
    int r0 = blockIdx.x * 32;
    int tid = threadIdx.x;
    int w  = tid >> 6;                     // wave id = K-eighth
    int l  = tid & 63;
    int lr = l & 31;                       // A row / B col / D col
    int kg = l >> 5;                       // k-group (0..1), 8 elems each
    const u16* arow = F   + (size_t)(r0 + lr) * FIN + kg * 8;
    const u16* b0p  = BtH + (size_t)lr * 3008 + kg * 8;
    const u16* b1p  = BtH + (size_t)(lr + 32) * 3008 + kg * 8;
    f32x16 acc0 = fzero16(), acc1 = fzero16();
    #pragma unroll 4
    for (int s = w; s < 188; s += 8) {
        int kk = s * 16;
        bf16x8 a;
        if (kk + kg * 8 < FIN) a = *(const bf16x8*)(arow + kk);
        else                   a = bzero8();
        bf16x8 b0 = *(const bf16x8*)(b0p + kk);   // Bt zero-padded to 3008
        bf16x8 b1 = *(const bf16x8*)(b1p + kk);
        acc0 = __builtin_amdgcn_mfma_f32_32x32x16_bf16(a, b0, acc0, 0, 0, 0);
        acc1 = __builtin_amdgcn_mfma_f32_32x32x16_bf16(a, b1, acc1, 0, 0, 0);
    }
    __shared__ float red[8][2048];         // 64 KB: per-wave 32x64 partials
    float* rp = red[w];
    #pragma unroll
    for (int reg = 0; reg < 16; reg++) {
        int row = (reg & 3) + 8 * (reg >> 2) + 4 * kg;
        rp[row * 64 + lr] = acc0[reg];
    }
    #pragma unroll
    for (int reg = 0; reg < 16; reg++) {
        int row = (reg & 3) + 8 * (reg >> 2) + 4 * kg;
        rp[row * 64 + 32 + lr] = acc1[reg];
    }
    __syncthreads();
    for (int i = tid; i < 2048; i += 512) {
        float s0 = 0.f;
        #pragma unroll
        for (int j = 0; j < 8; j++) s0 += red[j][i];
        X[(size_t)r0 * 64 + i] = s0;
    }
}

// ---- f32-input path: X = feat @ weight1 via split-bf16 3-term MFMA ----
// Round-9: COALESCED B staging (round-8 post-mortem: BtH[64][3008] made each
// B-stage instruction a 64-cache-line scatter -> ~2000 L2 transactions per
// step per CU, the real 6-round bottleneck). BtG granule-major layout makes
// the global image identical to the LDS image: lane l -> (g*64+l)*16B,
// consecutive lanes contiguous. Compute section byte-identical to round 8.
__global__ __launch_bounds__(256) void k_featgemm_mfma_f32(const int* __restrict__ flag,
    const void* __restrict__ F0v, const void* __restrict__ F1v,
    const u16* __restrict__ BtGH, const u16* __restrict__ BtGL,
    float* __restrict__ X0, float* __restrict__ X1)
{
    if (!*flag) return;                    // bf16 mode: handled by k_featgemm_mfma
    const float* F = (const float*)(blockIdx.y ? F1v : F0v);
    float* X = blockIdx.y ? X1 : X0;
    int tid = threadIdx.x;
    int w  = tid >> 6;                     // wave id
    int l  = tid & 63;
    int lr = l & 31;
    int kg = l >> 5;                       // k-group (0..1), 8 elems each
    int wr = w >> 1, wc = w & 1;           // 2x2 wave grid
    int r0 = blockIdx.x * 64;
    int chunk = blockIdx.z;                // 0..3
    int sbeg = chunk * 12;
    int nsteps = (chunk == 3) ? 11 : 12;

    __shared__ char lds[2][32768];         // per buf: A[16K] + BH[8K] + BL[8K]

    const float* Fb = F + (size_t)r0 * FIN;
    int arow = 32 * wr + lr;               // LDS A row this lane reads
    int acol = 32 * wc + lr;               // B col = output col
    int slin = (w * 16) * 256 + l * 16;    // linear A-LDS byte of lane's 16B
    f32x16 acc = fzero16();

    auto STAGE = [&](int s, int buf) {
        int kbase = (sbeg + s) * 64;
        int gbase = (sbeg + s) * 8;        // B granule base for this step
        char* base = lds[buf];
        #pragma unroll
        for (int j = 0; j < 4; j++) {      // A: swizzled source, linear dest
            int lin = slin + j * 1024;
            int row = lin >> 8;
            int off = (lin & 255) ^ ((row & 15) << 4);
            gload_lds16((const void*)(Fb + (size_t)row * FIN + kbase + (off >> 2)),
                        base + (w * 16 + j * 4) * 256);
        }
        #pragma unroll
        for (int j = 0; j < 2; j++) {      // BH: lane-contiguous granule copy
            int kgrp = w * 2 + j;
            gload_lds16((const void*)(BtGH + ((size_t)(gbase + kgrp) * 64 + l) * 8),
                        base + 16384 + kgrp * 1024);
        }
        #pragma unroll
        for (int j = 0; j < 2; j++) {      // BL
            int kgrp = w * 2 + j;
            gload_lds16((const void*)(BtGL + ((size_t)(gbase + kgrp) * 64 + l) * 8),
                        base + 24576 + kgrp * 1024);
        }
    };

    STAGE(0, 0);

    for (int s = 0; s < nsteps; ++s) {
        if (s + 1 < nsteps) {
            STAGE(s + 1, (s + 1) & 1);     // buf consumed at s-1, barrier'd
            asm volatile("s_waitcnt vmcnt(8)" ::: "memory");  // stage(s) done
        } else {
            asm volatile("s_waitcnt vmcnt(0)" ::: "memory");
        }
        __builtin_amdgcn_s_barrier();      // buf[s] globally ready
        const char* lb = lds[s & 1];
        const char* Bh = lb + 16384;
        const char* Bl = lb + 24576;
        #pragma unroll
        for (int s16 = 0; s16 < 4; s16++) {
            int offu = s16 * 64 + kg * 32;
            int o0 = offu        ^ ((arow & 15) << 4);
            int o1 = (offu + 16) ^ ((arow & 15) << 4);
            float4 a0 = *(const float4*)(lb + arow * 256 + o0);
            float4 a1 = *(const float4*)(lb + arow * 256 + o1);
            float av[8] = {a0.x, a0.y, a0.z, a0.w, a1.x, a1.y, a1.z, a1.w};
            bf16x8 ah, al;
            #pragma unroll
            for (int jj = 0; jj < 8; jj++) {
                __bf16 hv = (__bf16)av[jj];
                ah[jj] = hv;
                al[jj] = (__bf16)(av[jj] - (float)hv);   // exact residual
            }
            int kgrp = s16 * 2 + kg;
            bf16x8 H = *(const bf16x8*)(Bh + (kgrp * 64 + acol) * 16);
            bf16x8 L = *(const bf16x8*)(Bl + (kgrp * 64 + acol) * 16);
            acc = __builtin_amdgcn_mfma_f32_32x32x16_bf16(ah, H, acc, 0, 0, 0);
            acc = __builtin_amdgcn_mfma_f32_32x32x16_bf16(al, H, acc, 0, 0, 0);
            acc = __builtin_amdgcn_mfma_f32_32x32x16_bf16(ah, L, acc, 0, 0, 0);
        }
        __builtin_amdgcn_s_barrier();      // all waves done reading buf[s]
    }

    // 4-way K-chunk reduce (X pre-zeroed; L2-resident atomics)
    #pragma unroll
    for (int reg = 0; reg < 16; reg++) {
        int row = (reg & 3) + 8 * (reg >> 2) + 4 * kg;
        atomicAdd(&X[(size_t)(r0 + 32 * wr + row) * 64 + acol], acc[reg]);
    }
}

// ---- Wh = X @ att_W; s = Wh@a_src; d = Wh@a_dst; 4 rows/block, attW in LDS ----
__global__ __launch_bounds__(256) void k_whsd(
    const float* __restrict__ X1, const float* __restrict__ X2,
    const float* __restrict__ AW, const float* __restrict__ asrc, const float* __restrict__ adst,
    float* __restrict__ Wh1, float* __restrict__ Wh2,
    float* __restrict__ s1, float* __restrict__ s2,
    float* __restrict__ d1, float* __restrict__ d2)
{
    const float* X = blockIdx.y ? X2 : X1;
    float* Wh = blockIdx.y ? Wh2 : Wh1;
    float* sv = blockIdx.y ? s2 : s1;
    float* dv = blockIdx.y ? d2 : d1;
    __shared__ float aw[64][65];           // padded
    __shared__ float x[4][65];
    int tid = threadIdx.x;
    for (int i = tid; i < 4096; i += 256) aw[i >> 6][i & 63] = AW[i];
    int g = tid >> 6, c = tid & 63;
    int row = blockIdx.x * 4 + g;
    x[g][c] = X[(size_t)row * 64 + c];
    __syncthreads();
    float acc = 0.f;
    #pragma unroll 16
    for (int k = 0; k < 64; k++) acc += x[g][k] * aw[k][c];
    Wh[(size_t)row * 64 + c] = acc;
    float vs = acc * asrc[c];
    float vd = acc * adst[c];
    #pragma unroll
    for (int off = 32; off > 0; off >>= 1) { vs += __shfl_down(vs, off); vd += __shfl_down(vd, off); }
    if (c == 0) { sv[row] = vs; dv[row] = vd; }
}

// ---- masked softmax (rank-1 scores) + P @ Wh over CSR neighbors ----
__global__ __launch_bounds__(128) void k_attn(
    const int* __restrict__ cnt, const int* __restrict__ idx,
    const float* __restrict__ s1, const float* __restrict__ s2,
    const float* __restrict__ d1, const float* __restrict__ d2,
    const float* __restrict__ Wh1, const float* __restrict__ Wh2,
    float* __restrict__ A1, float* __restrict__ A2)
{
    const float* sp = blockIdx.y ? s2 : s1;
    const float* dp = blockIdx.y ? d2 : d1;
    const float* Wh = blockIdx.y ? Wh2 : Wh1;
    float* A = blockIdx.y ? A2 : A1;
    int row = blockIdx.x, tid = threadIdx.x;
    int n = cnt[row];
    __shared__ int js[MAXN];
    __shared__ float ps[MAXN];
    __shared__ float red2[2];
    __shared__ float ared[2][64];
    for (int k = tid; k < n; k += 128) js[k] = idx[(size_t)row * MAXN + k];
    __syncthreads();
    float si = sp[row];
    float m = -3.0e38f;
    for (int k = tid; k < n; k += 128) {
        float e = si + dp[js[k]];
        e = e > 0.f ? e : 0.2f * e;   // LeakyReLU(0.2)
        ps[k] = e;
        m = fmaxf(m, e);
    }
    #pragma unroll
    for (int off = 32; off > 0; off >>= 1) m = fmaxf(m, __shfl_down(m, off));
    if ((tid & 63) == 0) red2[tid >> 6] = m;
    __syncthreads();
    m = fmaxf(red2[0], red2[1]);
    __syncthreads();
    float zz = 0.f;
    for (int k = tid; k < n; k += 128) {
        float p = __expf(ps[k] - m);
        ps[k] = p;
        zz += p;
    }
    #pragma unroll
    for (int off = 32; off > 0; off >>= 1) zz += __shfl_down(zz, off);
    if ((tid & 63) == 0) red2[tid >> 6] = zz;
    __syncthreads();
    float Z = red2[0] + red2[1];
    Z = fmaxf(Z, 1e-20f);           // guard 0/0
    int f = tid & 63, half = tid >> 6;
    float acc = 0.f;
    for (int k = half; k < n; k += 2) acc += ps[k] * Wh[(size_t)js[k] * 64 + f];
    ared[half][f] = acc;
    __syncthreads();
    if (tid < 64) A[(size_t)row * 64 + f] = (ared[0][f] + ared[1][f]) / Z;
}

// ---- 3-layer MLP 64->256->128->64; 4 rows/block; writes z (f32) and hiden_emb (dual-dtype, y==0) ----
__global__ __launch_bounds__(256) void k_mlp(const int* __restrict__ flag,
    const float* __restrict__ A1, const float* __restrict__ A2,
    const float* __restrict__ W1, const float* __restrict__ b1,
    const float* __restrict__ W2, const float* __restrict__ b2,
    const float* __restrict__ W3, const float* __restrict__ b3,
    float* __restrict__ Z1, float* __restrict__ Z2, void* __restrict__ hidenv)
{
    const float* A = blockIdx.y ? A2 : A1;
    float* Z = blockIdx.y ? Z2 : Z1;
    int row0 = blockIdx.x * 4, tid = threadIdx.x;
    __shared__ float x[4][64], h1[4][256], h2[4][128];
    {
        int r = tid >> 6, c = tid & 63;
        x[r][c] = A[(size_t)(row0 + r) * 64 + c];
    }
    __syncthreads();
    {
        float a0 = b1[tid], a1v = a0, a2v = a0, a3v = a0;
        #pragma unroll 8
        for (int k = 0; k < 64; k++) {
            float w = W1[k * 256 + tid];
            a0 += x[0][k] * w; a1v += x[1][k] * w; a2v += x[2][k] * w; a3v += x[3][k] * w;
        }
        h1[0][tid] = fmaxf(a0, 0.f);  h1[1][tid] = fmaxf(a1v, 0.f);
        h1[2][tid] = fmaxf(a2v, 0.f); h1[3][tid] = fmaxf(a3v, 0.f);
    }
    __syncthreads();
    if (tid < 128) {
        float a0 = b2[tid], a1v = a0, a2v = a0, a3v = a0;
        #pragma unroll 8
        for (int k = 0; k < 256; k++) {
            float w = W2[k * 128 + tid];
            a0 += h1[0][k] * w; a1v += h1[1][k] * w; a2v += h1[2][k] * w; a3v += h1[3][k] * w;
        }
        h2[0][tid] = fmaxf(a0, 0.f);  h2[1][tid] = fmaxf(a1v, 0.f);
        h2[2][tid] = fmaxf(a2v, 0.f); h2[3][tid] = fmaxf(a3v, 0.f);
    }
    __syncthreads();
    if (tid < 64) {
        float a[4];
        a[0] = a[1] = a[2] = a[3] = b3[tid];
        #pragma unroll 8
        for (int k = 0; k < 128; k++) {
            float w = W3[k * 64 + tid];
            a[0] += h2[0][k] * w; a[1] += h2[1][k] * w; a[2] += h2[2][k] * w; a[3] += h2[3][k] * w;
        }
        bool isf = (*flag != 0);
        #pragma unroll
        for (int r = 0; r < 4; r++) {
            size_t ei = (size_t)(row0 + r) * 64 + tid;
            Z[ei] = a[r];
            if (blockIdx.y == 0) {
                if (isf) ((float*)hidenv)[ei] = a[r];
                else     ((u16*)hidenv)[ei] = f2bf(a[r]);
            }
        }
    }
}

// ---- T = adj @ z over CSR ----
__global__ __launch_bounds__(64) void k_spmm(
    const int* __restrict__ cnt, const int* __restrict__ idx,
    const float* __restrict__ Z, float* __restrict__ T)
{
    int row = blockIdx.x, f = threadIdx.x;
    int n = cnt[row];
    const int* ir = idx + (size_t)row * MAXN;
    float acc = 0.f;
    for (int k = 0; k < n; k++) acc += Z[(size_t)ir[k] * 64 + f];
    T[(size_t)row * 64 + f] = acc;
}

// ---- H = T @ weight2 via split-bf16 3-term MFMA -> out (dual-dtype store) ----
__global__ __launch_bounds__(256) void k_hgemm_mfma(const int* __restrict__ flag,
    const float* __restrict__ T, const u16* __restrict__ WH, const u16* __restrict__ WL,
    void* __restrict__ outv)
{
    bool isf = (*flag != 0);
    int tid = threadIdx.x;
    int w = tid >> 6, l = tid & 63, lr = l & 31, kg = l >> 5;
    int ct = blockIdx.y * 4 + w;
    if (ct >= 94) return;                  // wave-uniform; no barriers in kernel
    int r0 = blockIdx.x * 32, c0 = ct * 32;
    const float* tp = T + (size_t)(r0 + lr) * 64 + kg * 8;
    bf16x8 ah[4], al[4];
    #pragma unroll
    for (int s = 0; s < 4; s++) {
        float4 p0 = *(const float4*)(tp + s * 16);
        float4 p1 = *(const float4*)(tp + s * 16 + 4);
        float av[8] = {p0.x, p0.y, p0.z, p0.w, p1.x, p1.y, p1.z, p1.w};
        #pragma unroll
        for (int j = 0; j < 8; j++) {
            __bf16 hv = (__bf16)av[j];
            ah[s][j] = hv;
            al[s][j] = (__bf16)(av[j] - (float)hv);   // exact residual
        }
    }
    const u16* bh = WH + (size_t)(c0 + lr) * 64 + kg * 8;
    const u16* bl = WL + (size_t)(c0 + lr) * 64 + kg * 8;
    f32x16 acc = fzero16();
    #pragma unroll
    for (int s = 0; s < 4; s++) {
        bf16x8 vh = *(const bf16x8*)(bh + s * 16);
        bf16x8 vl = *(const bf16x8*)(bl + s * 16);
        acc = __builtin_amdgcn_mfma_f32_32x32x16_bf16(ah[s], vh, acc, 0, 0, 0);
        acc = __builtin_amdgcn_mfma_f32_32x32x16_bf16(al[s], vh, acc, 0, 0, 0);
        acc = __builtin_amdgcn_mfma_f32_32x32x16_bf16(ah[s], vl, acc, 0, 0, 0);
    }
    int col = c0 + lr;
    bool cok = col < FIN;
    #pragma unroll
    for (int reg = 0; reg < 16; reg++) {
        int row = (reg & 3) + 8 * (reg >> 2) + 4 * kg;
        size_t ei = 262144 + (size_t)(r0 + row) * FIN + col;
        if (cok) {
            if (isf) ((float*)outv)[ei] = acc[reg];
            else     ((u16*)outv)[ei] = f2bf(acc[reg]);
        }
    }
}

// ---- readout: mean over graph_neigh nbrs of relu(z), L2 normalize, sigmoid ----
__global__ __launch_bounds__(64) void k_readout(
    const int* __restrict__ cnt, const int* __restrict__ idx,
    const float* __restrict__ Z1, const float* __restrict__ Z2,
    float* __restrict__ G1, float* __restrict__ G2)
{
    const float* Z = blockIdx.y ? Z2 : Z1;
    float* G = blockIdx.y ? G2 : G1;
    int row = blockIdx.x, f = threadIdx.x;
    int n = cnt[row];
    const int* ir = idx + (size_t)row * MAXN;
    float acc = 0.f;
    for (int k = 0; k < n; k++) acc += fmaxf(Z[(size_t)ir[k] * 64 + f], 0.f);
    acc /= (float)(n > 0 ? n : 1);
    float sq = acc * acc;
    #pragma unroll
    for (int off = 32; off > 0; off >>= 1) sq += __shfl_down(sq, off);
    sq = __shfl(sq, 0);
    float nrm = fmaxf(sqrtf(sq), 1e-12f);
    float v = acc / nrm;
    G[(size_t)row * 64 + f] = 1.f / (1.f + __expf(-v));
}

// ---- discriminator MLP 64->128->64; 4 rows/block; on {relu(z), relu(z_a), g, g_a} ----
__global__ __launch_bounds__(128) void k_dmlp(
    const float* __restrict__ z, const float* __restrict__ za,
    const float* __restrict__ g, const float* __restrict__ ga,
    const float* __restrict__ W1, const float* __restrict__ b1,
    const float* __restrict__ W2, const float* __restrict__ b2,
    float* __restrict__ De, float* __restrict__ Dea,
    float* __restrict__ Dg, float* __restrict__ Dga)
{
    int w = blockIdx.y;
    const float* X = (w == 0) ? z : (w == 1) ? za : (w == 2) ? g : ga;
    float* O = (w == 0) ? De : (w == 1) ? Dea : (w == 2) ? Dg : Dga;
    int doRelu = (w < 2);
    int row0 = blockIdx.x * 4, tid = threadIdx.x;
    __shared__ float x[4][64], h1[4][128];
    for (int i = tid; i < 256; i += 128) {
        int r = i >> 6, c = i & 63;
        float v = X[(size_t)(row0 + r) * 64 + c];
        x[r][c] = doRelu ? fmaxf(v, 0.f) : v;
    }
    __syncthreads();
    {
        float a0 = b1[tid], a1v = a0, a2v = a0, a3v = a0;
        #pragma unroll 8
        for (int k = 0; k < 64; k++) {
            float w_ = W1[k * 128 + tid];
            a0 += x[0][k] * w_; a1v += x[1][k] * w_; a2v += x[2][k] * w_; a3v += x[3][k] * w_;
        }
        h1[0][tid] = fmaxf(a0, 0.f);  h1[1][tid] = fmaxf(a1v, 0.f);
        h1[2][tid] = fmaxf(a2v, 0.f); h1[3][tid] = fmaxf(a3v, 0.f);
    }
    __syncthreads();
    if (tid < 64) {
        float a[4];
        a[0] = a[1] = a[2] = a[3] = b2[tid];
        #pragma unroll 8
        for (int k = 0; k < 128; k++) {
            float w_ = W2[k * 64 + tid];
            a[0] += h1[0][k] * w_; a[1] += h1[1][k] * w_; a[2] += h1[2][k] * w_; a[3] += h1[3][k] * w_;
        }
        #pragma unroll
        for (int r = 0; r < 4; r++) O[(size_t)(row0 + r) * 64 + tid] = a[r];
    }
}

// ---- bilinear stage 1: V = Y @ BW^T for Y in {Dg, Dga}; BW cached in LDS ----
__global__ __launch_bounds__(256) void k_bilin_pre(
    const float* __restrict__ Dg, const float* __restrict__ Dga,
    const float* __restrict__ BW, float* __restrict__ V1, float* __restrict__ V2)
{
    const float* Y = blockIdx.y ? Dga : Dg;
    float* V = blockIdx.y ? V2 : V1;
    __shared__ float bw[64][65];           // padded
    __shared__ float y[4][65];
    int tid = threadIdx.x;
    for (int i = tid; i < 4096; i += 256) bw[i >> 6][i & 63] = BW[i];
    int g = tid >> 6, k = tid & 63;
    int rbase = blockIdx.x * 64;
    for (int it = 0; it < 16; it++) {
        __syncthreads();
        int r = rbase + it * 4 + g;
        y[g][k] = Y[(size_t)r * 64 + k];
        __syncthreads();
        float acc = 0.f;
        #pragma unroll 16
        for (int j = 0; j < 64; j++) acc += y[g][j] * bw[k][j];
        V[(size_t)r * 64 + k] = acc;       // V[r][k] = (BW @ y_r)[k]
    }
}

// ---- bilinear stage 2: out = dot(x_r, V_r) + b ; 4 rows/block, dual-dtype ----
__global__ __launch_bounds__(256) void k_bilin_dot(const int* __restrict__ flag,
    const float* __restrict__ De, const float* __restrict__ Dea,
    const float* __restrict__ V1, const float* __restrict__ V2,
    const float* __restrict__ bb, void* __restrict__ outv)
{
    int w = blockIdx.y;
    const float* X = (w == 0 || w == 3) ? De : Dea;
    const float* V = (w <= 1) ? V1 : V2;
    size_t bse = (w <= 1) ? (size_t)12550144 : (size_t)12558336;
    int col = (w == 0 || w == 2) ? 0 : 1;
    int g = threadIdx.x >> 6, k = threadIdx.x & 63;
    int row = blockIdx.x * 4 + g;
    float v = X[(size_t)row * 64 + k] * V[(size_t)row * 64 + k];
    #pragma unroll
    for (int off = 32; off > 0; off >>= 1) v += __shfl_down(v, off);
    if (k == 0) {
        float r = v + bb[0];
        size_t ei = bse + (size_t)row * 2 + col;
        if (*flag) ((float*)outv)[ei] = r;
        else       ((u16*)outv)[ei] = f2bf(r);
    }
}

extern "C" void kernel_launch(void* const* d_in, const int* in_sizes, int n_in,
                              void* d_out, int out_size, void* d_ws, size_t ws_size,
                              hipStream_t stream) {
    const void* feat   = d_in[0];
    const void* feat_a = d_in[1];
    const void* adj    = d_in[2];
    const void* gn     = d_in[3];
    const void* w1     = d_in[4];
    const void* w2     = d_in[5];
    const void* attW   = d_in[6];
    const void* a_src  = d_in[7];
    const void* a_dst  = d_in[8];
    const void* mW1    = d_in[9];
    const void* mb1    = d_in[10];
    const void* mW2    = d_in[11];
    const void* mb2    = d_in[12];
    const void* mW3    = d_in[13];
    const void* mb3    = d_in[14];
    const void* dW1    = d_in[15];
    const void* db1    = d_in[16];
    const void* dW2    = d_in[17];
    const void* db2    = d_in[18];
    const void* bW     = d_in[19];
    const void* bb     = d_in[20];
    (void)in_sizes; (void)n_in; (void)out_size;

    // ---- d_ws: flag + T + W2tH/W2tL (~1.82 MB total) ----
    char* wsb = (char*)d_ws;
    int*   flag = (int*)wsb;                        // 4 B (pad 256)
    float* T    = (float*)(wsb + 256);              // 1,048,576 B
    u16*   W2tH = (u16*)(wsb + 256 + 1048576);      // 385,024 B
    u16*   W2tL = W2tH + 3008 * 64;                 // 385,024 B
    (void)ws_size;

    // ---- scratch arena at dtype-independent byte window of d_out ----
    char* sc = (char*)d_out + 1048576;
    size_t soff = 0;
    auto salloc = [&](size_t nbytes) -> void* {
        void* p = (void*)(sc + soff);
        soff += (nbytes + 255) & ~(size_t)255;
        return p;
    };
    const size_t NV = (size_t)NN * 64;
    float* wA   = (float*)salloc((size_t)274689 * 4);  // 16-segment f32 weight arena
    int*   aCnt = (int*)salloc(NN * 4);
    int*   gCnt = (int*)salloc(NN * 4);
    int*   aIdx = (int*)salloc((size_t)NN * MAXN * 4);
    int*   gIdx = (int*)salloc((size_t)NN * MAXN * 4);
    float* X1  = (float*)salloc(NV * 4);
    float* X2  = (float*)salloc(NV * 4);   // contiguous with X1 (NV*4 is 256-mult)
    float* Wh1 = (float*)salloc(NV * 4);
    float* Wh2 = (float*)salloc(NV * 4);
    float* A1  = (float*)salloc(NV * 4);
    float* A2  = (float*)salloc(NV * 4);
    float* z   = (float*)salloc(NV * 4);
    float* za  = (float*)salloc(NV * 4);
    float* g   = (float*)salloc(NV * 4);
    float* ga  = (float*)salloc(NV * 4);
    float* De  = (float*)salloc(NV * 4);
    float* Dea = (float*)salloc(NV * 4);
    float* Dg  = (float*)salloc(NV * 4);
    float* Dga = (float*)salloc(NV * 4);
    float* s1  = (float*)salloc(NN * 4);
    float* s2  = (float*)salloc(NN * 4);
    float* d1  = (float*)salloc(NN * 4);
    float* d2  = (float*)salloc(NN * 4);
    // soff ~= 20.1 MB < 20.15 MB window: fits.

    float* w1f   = wA + 0;
    float* attWf = wA + 192000;
    float* asrcf = wA + 196096;
    float* adstf = wA + 196160;
    float* mW1f  = wA + 196224;
    float* mb1f  = wA + 212608;
    float* mW2f  = wA + 212864;
    float* mb2f  = wA + 245632;
    float* mW3f  = wA + 245760;
    float* mb3f  = wA + 253952;
    float* dW1f  = wA + 254016;
    float* db1f  = wA + 262208;
    float* dW2f  = wA + 262336;
    float* db2f  = wA + 270528;
    float* bWf   = wA + 270592;
    float* bbf   = wA + 274688;

    // W1 images park in dead slots (all consumed before k_dmlp writes them):
    //   BtGH (granule-major H, 385 KB) -> De
    //   BtGL (granule-major L, 385 KB) -> Dea
    //   BtHold (bf16-path [64][3008] H, 385 KB) -> Dg
    u16* BtGH   = (u16*)De;
    u16* BtGL   = (u16*)Dea;
    u16* BtHold = (u16*)Dg;

    k_detect<<<1, 1024, 0, stream>>>((const u16*)feat, flag);
    k_convw<<<dim3(750, 16), 256, 0, stream>>>(flag,
        w1, attW, a_src, a_dst, mW1, mb1, mW2, mb2, mW3, mb3,
        dW1, db1, dW2, db2, bW, bb, wA);
    k_convwt<<<dim3(753, 3), 256, 0, stream>>>(flag, w1, w2, BtGH, BtGL, W2tH, W2tL, BtHold);
    k_build_csr<<<dim3(NN, 2), 256, 0, stream>>>(flag, adj, gn, aCnt, aIdx, gCnt, gIdx);
    hipMemsetAsync(X1, 0, 2 * NV * 4, stream);   // zero X1+X2 for f32 K-split atomics
    k_featgemm_mfma<<<dim3(NN / 32, 2), 512, 0, stream>>>(flag, feat, feat_a, BtHold, X1, X2);
    k_featgemm_mfma_f32<<<dim3(NN / 64, 2, 4), 256, 0, stream>>>(flag, feat, feat_a, BtGH, BtGL, X1, X2);
    k_whsd<<<dim3(NN / 4, 2), 256, 0, stream>>>(X1, X2, attWf, asrcf, adstf, Wh1, Wh2, s1, s2, d1, d2);
    k_attn<<<dim3(NN, 2), 128, 0, stream>>>(aCnt, aIdx, s1, s2, d1, d2, Wh1, Wh2, A1, A2);
    k_mlp<<<dim3(NN / 4, 2), 256, 0, stream>>>(flag, A1, A2, mW1f, mb1f, mW2f, mb2f, mW3f, mb3f, z, za, d_out);
    k_readout<<<dim3(NN, 2), 64, 0, stream>>>(gCnt, gIdx, z, za, g, ga);
    k_dmlp<<<dim3(NN / 4, 4), 128, 0, stream>>>(z, za, g, ga, dW1f, db1f, dW2f, db2f, De, Dea, Dg, Dga);
    k_bilin_pre<<<dim3(64, 2), 256, 0, stream>>>(Dg, Dga, bWf, A1, A2);   // A1/A2 dead after k_mlp
    k_bilin_dot<<<dim3(NN / 4, 4), 256, 0, stream>>>(flag, De, Dea, A1, A2, bbf, d_out);
    k_spmm<<<NN, 64, 0, stream>>>(aCnt, aIdx, z, T);
    k_hgemm_mfma<<<dim3(NN / 32, 24), 256, 0, stream>>>(flag, T, W2tH, W2tL, d_out);
}